// Round 15
// baseline (407.247 us; speedup 1.0000x reference)
//
#include <hip/hip_runtime.h>
#include <cmath>

#define BB 8
#define NN 4096
#define DD 64
#define KK 8
#define NCLS 2

constexpr float LNEPS = 1e-5f;
constexpr float BNRS = 0.9999950000374994f;      // 1/sqrt(1+1e-5)
constexpr float INVSQRT2 = 0.70710678118654752440f;

// knn decomposition: 64 queries/block x 16 candidate-splits (one per wave)
#define QPB 64
#define SPLITS 16
#define SUBSET 64     // pass-1 subset per split (16*64 = 1024-point bound set)

__device__ __forceinline__ float wave_sum(float v) {
#pragma unroll
  for (int m = 32; m > 0; m >>= 1) v += __shfl_xor(v, m, 64);
  return v;
}

__device__ __forceinline__ float gelu_exact(float x) {
  return 0.5f * x * (1.0f + erff(x * INVSQRT2));
}

// identical in both knn passes -> bit-identical distances
__device__ __forceinline__ float dist2(float4 q, float4 p) {
  float dot = fmaf(q.x, p.x, fmaf(q.y, p.y, q.z * p.z));
  return fmaf(-2.0f, dot, q.w + p.w);
}

// ---------------------------------------------------------------- zero g
__global__ void zero_kernel(float* g) { g[threadIdx.x] = 0.0f; }

// ---------------------------------------------------------------- embed: h = relu(x@ew1+eb1)@ew2+eb2
__global__ __launch_bounds__(256) void embed_kernel(
    const float* __restrict__ x, const float* __restrict__ ew1, const float* __restrict__ eb1,
    const float* __restrict__ ew2, const float* __restrict__ eb2, float* __restrict__ h) {
  __shared__ float h1[4][DD];
  int w = threadIdx.x >> 6, c = threadIdx.x & 63;
  int pt = ((blockIdx.x & 7) << 12) + (blockIdx.x >> 3) * 4 + w;
  const float* xp = x + (size_t)pt * 3;
  float x0 = xp[0], x1 = xp[1], x2 = xp[2];
  float a = fmaf(x0, ew1[c], fmaf(x1, ew1[64 + c], fmaf(x2, ew1[128 + c], eb1[c])));
  h1[w][c] = fmaxf(a, 0.0f);
  float s = eb2[c];
#pragma unroll 8
  for (int d = 0; d < DD; d++) s = fmaf(h1[w][d], ew2[d * 64 + c], s);
  h[(size_t)pt * 64 + c] = s;
}

// ---------------------------------------------------------------- knn prep: ppg[b*N+j] = (x,y,z,|p|^2)
__global__ __launch_bounds__(256) void knn_prep_kernel(const float* __restrict__ x,
                                                       float4* __restrict__ ppg) {
  int i = ((blockIdx.x & 7) << 12) + (blockIdx.x >> 3) * 256 + threadIdx.x;
  float a0 = x[3 * i + 0], a1 = x[3 * i + 1], a2 = x[3 * i + 2];
  ppg[i] = make_float4(a0, a1, a2, a0 * a0 + a1 * a1 + a2 * a2);
}

// ---------------------------------------------------------------- knn: exact top-8 (stable ties), 2-pass
__global__ __launch_bounds__(1024) void knn_kernel(const float4* __restrict__ ppg,
                                                   int* __restrict__ idx) {
  __shared__ union {
    float v[SPLITS * 8][QPB];       // pass-1 value lists
    double k[SPLITS * 8][QPB];      // pass-2 key lists (64 KB)
  } mb;
  __shared__ float thrq[QPB];
  int b = blockIdx.x & 7;           // XCD-pinned batch
  int qbase = (blockIdx.x >> 3) * QPB;
  const float4* pb = ppg + (size_t)b * NN;
  int ql = threadIdx.x & 63;
  int sp = __builtin_amdgcn_readfirstlane(threadIdx.x >> 6);  // wave id = split id (SGPR)
  float4 qp = pb[qbase + ql];
  const float4* cp = pb + sp * (NN / SPLITS);                 // scalar base

  // ---- pass 1: branchless top-8 distances over SUBSET candidates
  float bd[8];
#pragma unroll
  for (int u = 0; u < 8; u++) bd[u] = INFINITY;
#pragma unroll 4
  for (int jj = 0; jj < SUBSET; ++jj) {
    float d2 = dist2(qp, cp[jj]);
#pragma unroll
    for (int u = 7; u > 0; --u) bd[u] = fminf(bd[u], fmaxf(bd[u - 1], d2));
    bd[0] = fminf(bd[0], d2);
  }
#pragma unroll
  for (int u = 0; u < 8; u++) mb.v[sp * 8 + u][ql] = bd[u];
  __syncthreads();

  // ---- U merge stage 1
  if (sp < 8) {
    float cd[8];
#pragma unroll
    for (int u = 0; u < 8; u++) cd[u] = INFINITY;
    int base = sp * 16;
#pragma unroll
    for (int e = 0; e < 16; e++) {
      float vv = mb.v[base + e][ql];
#pragma unroll
      for (int u = 7; u > 0; --u) cd[u] = fminf(cd[u], fmaxf(cd[u - 1], vv));
      cd[0] = fminf(cd[0], vv);
    }
#pragma unroll
    for (int u = 0; u < 8; u++) mb.v[base + u][ql] = cd[u];
  }
  __syncthreads();

  // ---- U merge stage 2
  if (sp == 0) {
    float cd[8];
#pragma unroll
    for (int u = 0; u < 8; u++) cd[u] = INFINITY;
    for (int m = 0; m < 8; m++) {
      for (int e = 0; e < 8; e++) {
        float vv = mb.v[m * 16 + e][ql];
        if (__all(vv >= cd[7])) break;
#pragma unroll
        for (int u = 7; u > 0; --u) cd[u] = fminf(cd[u], fmaxf(cd[u - 1], vv));
        cd[0] = fminf(cd[0], vv);
      }
    }
    thrq[ql] = cd[7];
  }
  __syncthreads();
  float U = thrq[ql];

  // ---- init key slots
#pragma unroll
  for (int u = 0; u < 8; u++) mb.k[sp * 8 + u][ql] = INFINITY;

  // ---- pass 2: FIFO-collect hits (d2<=U) per split; overflow -> replace-max
  int cnt = 0;
#pragma unroll 4
  for (int jj = 0; jj < NN / SPLITS; ++jj) {
    float d2 = dist2(qp, cp[jj]);
    if (d2 <= U) {
      double key = __hiloint2double(__float_as_int(d2), sp * (NN / SPLITS) + jj);
      if (cnt < 8) {
        mb.k[sp * 8 + cnt][ql] = key;
        cnt++;
      } else {
        double mx = mb.k[sp * 8 + 0][ql];
        int mi = 0;
#pragma unroll
        for (int u = 1; u < 8; u++) {
          double tv = mb.k[sp * 8 + u][ql];
          if (tv > mx) { mx = tv; mi = u; }
        }
        if (key < mx) mb.k[sp * 8 + mi][ql] = key;
      }
    }
  }
  __syncthreads();

  // ---- key merge stage 1 (network accepts unsorted input; output sorted)
  if (sp < 8) {
    double cd[8];
#pragma unroll
    for (int u = 0; u < 8; u++) cd[u] = INFINITY;
    int base = sp * 16;
#pragma unroll
    for (int e = 0; e < 16; e++) {
      double key = mb.k[base + e][ql];
#pragma unroll
      for (int u = 7; u > 0; --u) cd[u] = fmin(cd[u], fmax(cd[u - 1], key));
      cd[0] = fmin(cd[0], key);
    }
#pragma unroll
    for (int u = 0; u < 8; u++) mb.k[base + u][ql] = cd[u];
  }
  __syncthreads();

  // ---- key merge stage 2 + write
  if (sp == 0) {
    double cd[8];
#pragma unroll
    for (int u = 0; u < 8; u++) cd[u] = INFINITY;
    for (int m = 0; m < 8; m++) {
      for (int e = 0; e < 8; e++) {
        double key = mb.k[m * 16 + e][ql];
        if (__all(key >= cd[7])) break;
#pragma unroll
        for (int u = 7; u > 0; --u) cd[u] = fmin(cd[u], fmax(cd[u - 1], key));
        cd[0] = fmin(cd[0], key);
      }
    }
    int* op = idx + ((size_t)b * NN + qbase + ql) * 8;
#pragma unroll
    for (int u = 0; u < 8; u++) op[u] = __double2loint(cd[u]);
  }
}

// ---------------------------------------------------------------- qkv projection: 2-wave blocks (VGPR<=64), 4 points/wave
// LDS hb wave-private -> no barriers; 2 waves/block x reg-bound 8/EU -> 32 waves/CU possible.
__global__ __launch_bounds__(128, 8) void qkv_kernel(
    const float* __restrict__ h, const float* __restrict__ wq, const float* __restrict__ bq,
    const float* __restrict__ wk, const float* __restrict__ bk,
    const float* __restrict__ wv, const float* __restrict__ bv,
    float* __restrict__ q, float* __restrict__ k, float* __restrict__ v) {
  __shared__ __attribute__((aligned(16))) float hb[2][DD][4];
  int w = threadIdx.x >> 6, c = threadIdx.x & 63;
  int b = blockIdx.x & 7, pos = blockIdx.x >> 3;   // 512 block-positions per batch
  int p0 = (b << 12) + (pos * 2 + w) * 4;
#pragma unroll
  for (int i = 0; i < 4; i++) hb[w][c][i] = h[(size_t)(p0 + i) * 64 + c];
  float bqc = bq[c], bkc = bk[c], bvc = bv[c];
  float aq[4], ak[4], av[4];
#pragma unroll
  for (int i = 0; i < 4; i++) { aq[i] = bqc; ak[i] = bkc; av[i] = bvc; }
#pragma unroll 4
  for (int d = 0; d < DD; d++) {
    float wq_ = wq[d * 64 + c], wk_ = wk[d * 64 + c], wv_ = wv[d * 64 + c];
    float4 hh = *(const float4*)&hb[w][d][0];
    aq[0] = fmaf(hh.x, wq_, aq[0]); aq[1] = fmaf(hh.y, wq_, aq[1]);
    aq[2] = fmaf(hh.z, wq_, aq[2]); aq[3] = fmaf(hh.w, wq_, aq[3]);
    ak[0] = fmaf(hh.x, wk_, ak[0]); ak[1] = fmaf(hh.y, wk_, ak[1]);
    ak[2] = fmaf(hh.z, wk_, ak[2]); ak[3] = fmaf(hh.w, wk_, ak[3]);
    av[0] = fmaf(hh.x, wv_, av[0]); av[1] = fmaf(hh.y, wv_, av[1]);
    av[2] = fmaf(hh.z, wv_, av[2]); av[3] = fmaf(hh.w, wv_, av[3]);
  }
#pragma unroll
  for (int i = 0; i < 4; i++) {
    q[(size_t)(p0 + i) * 64 + c] = aq[i];
    k[(size_t)(p0 + i) * 64 + c] = ak[i];
    v[(size_t)(p0 + i) * 64 + c] = av[i];
  }
}

// ---------------------------------------------------------------- fused attention+ffn: 2-wave blocks (VGPR<=64), 2 points/wave
// LDS slices wave-private -> no barriers. attn -> t (regs) -> ffn -> h, point-local.
__global__ __launch_bounds__(128, 8) void attn_ffn_kernel(
    const float* __restrict__ x, float* h,
    const float* __restrict__ q, const float* __restrict__ kk, const float* __restrict__ vv,
    const int* __restrict__ idx,
    const float* __restrict__ pw1, const float* __restrict__ pb1,
    const float* __restrict__ pw2, const float* __restrict__ pb2,
    const float* __restrict__ aw, const float* __restrict__ ab,
    const float* __restrict__ ow, const float* __restrict__ ob,
    const float* __restrict__ l1g, const float* __restrict__ l1b,
    const float* __restrict__ fw1, const float* __restrict__ fb1,
    const float* __restrict__ fw2, const float* __restrict__ fb2,
    const float* __restrict__ l2g, const float* __restrict__ l2b) {
  __shared__ __attribute__((aligned(16))) float h1b[2][2][DD][8];   // 8KB
  __shared__ __attribute__((aligned(16))) float outb[2][2][DD];     // 1KB
  __shared__ __attribute__((aligned(8)))  float tb[2][DD][2];       // 1KB
  __shared__ __attribute__((aligned(8)))  float hb2[2][128][2];     // 2KB
  int w = threadIdx.x >> 6, c = threadIdx.x & 63;
  int b = blockIdx.x & 7;                          // XCD-pinned batch
  int n0 = (blockIdx.x >> 3) * 4 + w * 2;          // 1024 block-positions per batch
  int p0 = (b << 12) + n0;
  const float* xb = x + (size_t)b * NN * 3;
  float w1c0 = pw1[c], w1c1 = pw1[64 + c], w1c2 = pw1[128 + c], b1c = pb1[c];
  float pb2c = pb2[c], lawc = aw[c], lobc = ob[c], g1c = l1g[c], bt1c = l1b[c];
  float lab = ab[0];
  float hs0 = h[(size_t)p0 * 64 + c], hs1 = h[(size_t)(p0 + 1) * 64 + c];
  float qs0 = q[(size_t)p0 * 64 + c], qs1 = q[(size_t)(p0 + 1) * 64 + c];
  int nb[2][8];
#pragma unroll
  for (int u = 0; u < 8; u++) {
    nb[0][u] = idx[(size_t)p0 * 8 + u];
    nb[1][u] = idx[(size_t)(p0 + 1) * 8 + u];
  }
  // ---- prefetch all k/v gather rows NOW; latency hides under pe1+pe2 compute
  float kv0[8], kv1[8], vg0[8], vg1[8];
#pragma unroll
  for (int u = 0; u < 8; u++) {
    kv0[u] = kk[((size_t)(b << 12) + nb[0][u]) * 64 + c];
    kv1[u] = kk[((size_t)(b << 12) + nb[1][u]) * 64 + c];
    vg0[u] = vv[((size_t)(b << 12) + nb[0][u]) * 64 + c];
    vg1[u] = vv[((size_t)(b << 12) + nb[1][u]) * 64 + c];
  }
#pragma unroll
  for (int pt = 0; pt < 2; ++pt) {
    int n = n0 + pt;
    float px0 = xb[n * 3 + 0], px1 = xb[n * 3 + 1], px2 = xb[n * 3 + 2];
    float h1v[8];
#pragma unroll
    for (int u = 0; u < 8; u++) {
      int m = nb[pt][u];
      float d0 = px0 - xb[m * 3 + 0], d1 = px1 - xb[m * 3 + 1], d2 = px2 - xb[m * 3 + 2];
      h1v[u] = fmaxf(fmaf(d0, w1c0, fmaf(d1, w1c1, fmaf(d2, w1c2, b1c))), 0.0f);
    }
    *(float4*)&h1b[w][pt][c][0] = make_float4(h1v[0], h1v[1], h1v[2], h1v[3]);
    *(float4*)&h1b[w][pt][c][4] = make_float4(h1v[4], h1v[5], h1v[6], h1v[7]);
  }
  float acc0[8], acc1[8];
#pragma unroll
  for (int u = 0; u < 8; u++) { acc0[u] = pb2c; acc1[u] = pb2c; }
#pragma unroll 2
  for (int d = 0; d < DD; d++) {
    float wv_ = pw2[d * 64 + c];
    float4 a0 = *(const float4*)&h1b[w][0][d][0];
    float4 b0 = *(const float4*)&h1b[w][0][d][4];
    float4 a1 = *(const float4*)&h1b[w][1][d][0];
    float4 b1 = *(const float4*)&h1b[w][1][d][4];
    acc0[0] = fmaf(a0.x, wv_, acc0[0]); acc0[1] = fmaf(a0.y, wv_, acc0[1]);
    acc0[2] = fmaf(a0.z, wv_, acc0[2]); acc0[3] = fmaf(a0.w, wv_, acc0[3]);
    acc0[4] = fmaf(b0.x, wv_, acc0[4]); acc0[5] = fmaf(b0.y, wv_, acc0[5]);
    acc0[6] = fmaf(b0.z, wv_, acc0[6]); acc0[7] = fmaf(b0.w, wv_, acc0[7]);
    acc1[0] = fmaf(a1.x, wv_, acc1[0]); acc1[1] = fmaf(a1.y, wv_, acc1[1]);
    acc1[2] = fmaf(a1.z, wv_, acc1[2]); acc1[3] = fmaf(a1.w, wv_, acc1[3]);
    acc1[4] = fmaf(b1.x, wv_, acc1[4]); acc1[5] = fmaf(b1.y, wv_, acc1[5]);
    acc1[6] = fmaf(b1.z, wv_, acc1[6]); acc1[7] = fmaf(b1.w, wv_, acc1[7]);
  }
  float lg0[8], lg1[8];
#pragma unroll
  for (int u = 0; u < 8; u++) {
    lg0[u] = wave_sum((qs0 - kv0[u] + acc0[u]) * lawc) + lab;
    lg1[u] = wave_sum((qs1 - kv1[u] + acc1[u]) * lawc) + lab;
  }
  float mx0 = lg0[0], mx1 = lg1[0];
#pragma unroll
  for (int u = 1; u < 8; u++) { mx0 = fmaxf(mx0, lg0[u]); mx1 = fmaxf(mx1, lg1[u]); }
  float s0 = 0.0f, s1 = 0.0f;
#pragma unroll
  for (int u = 0; u < 8; u++) {
    lg0[u] = expf(lg0[u] - mx0); s0 += lg0[u];
    lg1[u] = expf(lg1[u] - mx1); s1 += lg1[u];
  }
  float i0 = 1.0f / s0, i1 = 1.0f / s1;
  float out0 = 0.0f, out1 = 0.0f;
#pragma unroll
  for (int u = 0; u < 8; u++) {
    out0 = fmaf(lg0[u] * i0, vg0[u] + acc0[u], out0);
    out1 = fmaf(lg1[u] * i1, vg1[u] + acc1[u], out1);
  }
  outb[w][0][c] = out0; outb[w][1][c] = out1;
  float at0 = lobc, at1 = lobc;
#pragma unroll 4
  for (int d = 0; d < DD; d += 4) {
    float4 o0 = *(const float4*)&outb[w][0][d];
    float4 o1 = *(const float4*)&outb[w][1][d];
    float wa = ow[(d + 0) * 64 + c], wb = ow[(d + 1) * 64 + c];
    float wc = ow[(d + 2) * 64 + c], wd = ow[(d + 3) * 64 + c];
    at0 = fmaf(o0.x, wa, at0); at0 = fmaf(o0.y, wb, at0);
    at0 = fmaf(o0.z, wc, at0); at0 = fmaf(o0.w, wd, at0);
    at1 = fmaf(o1.x, wa, at1); at1 = fmaf(o1.y, wb, at1);
    at1 = fmaf(o1.z, wc, at1); at1 = fmaf(o1.w, wd, at1);
  }
  float t0v, t1v;
  {
    float res = at0 + hs0;
    float mean = wave_sum(res) * (1.0f / 64.0f);
    float dv = res - mean;
    float var = wave_sum(dv * dv) * (1.0f / 64.0f);
    float ivr = 1.0f / sqrtf(var + LNEPS);
    t0v = fmaf(g1c, dv * ivr, bt1c);
  }
  {
    float res = at1 + hs1;
    float mean = wave_sum(res) * (1.0f / 64.0f);
    float dv = res - mean;
    float var = wave_sum(dv * dv) * (1.0f / 64.0f);
    float ivr = 1.0f / sqrtf(var + LNEPS);
    t1v = fmaf(g1c, dv * ivr, bt1c);
  }
  // ================ ffn (fused, point-local; math identical)
  tb[w][c][0] = t0v; tb[w][c][1] = t1v;
  float fb1a = fb1[c], fb1b = fb1[64 + c];
  float hA0 = fb1a, hA1 = fb1a, hB0 = fb1b, hB1 = fb1b;
#pragma unroll 4
  for (int d = 0; d < DD; d++) {
    float w0 = fw1[d * 128 + c], w1 = fw1[d * 128 + 64 + c];
    float2 yv = *(const float2*)&tb[w][d][0];
    hA0 = fmaf(yv.x, w0, hA0); hA1 = fmaf(yv.y, w0, hA1);
    hB0 = fmaf(yv.x, w1, hB0); hB1 = fmaf(yv.y, w1, hB1);
  }
  hA0 = gelu_exact(hA0); hA1 = gelu_exact(hA1);
  hB0 = gelu_exact(hB0); hB1 = gelu_exact(hB1);
  hb2[w][c][0] = hA0; hb2[w][c][1] = hA1;
  hb2[w][64 + c][0] = hB0; hb2[w][64 + c][1] = hB1;
  float fb2c = fb2[c], g2c = l2g[c], bt2c = l2b[c];
  float o0 = fb2c, o1 = fb2c;
#pragma unroll 4
  for (int j = 0; j < 128; j++) {
    float wv_ = fw2[j * 64 + c];
    float2 hv = *(const float2*)&hb2[w][j][0];
    o0 = fmaf(hv.x, wv_, o0); o1 = fmaf(hv.y, wv_, o1);
  }
  {
    float r = t0v + o0;
    float mean = wave_sum(r) * (1.0f / 64.0f);
    float dv = r - mean;
    float var = wave_sum(dv * dv) * (1.0f / 64.0f);
    float ivr = 1.0f / sqrtf(var + LNEPS);
    h[(size_t)p0 * 64 + c] = fmaf(g2c, dv * ivr, bt2c);
  }
  {
    float r = t1v + o1;
    float mean = wave_sum(r) * (1.0f / 64.0f);
    float dv = r - mean;
    float var = wave_sum(dv * dv) * (1.0f / 64.0f);
    float ivr = 1.0f / sqrtf(var + LNEPS);
    h[(size_t)(p0 + 1) * 64 + c] = fmaf(g2c, dv * ivr, bt2c);
  }
}

// ---------------------------------------------------------------- classifier proj + blockwise max-pool (XCD-pinned)
__global__ __launch_bounds__(256) void cls_kernel(
    const float* __restrict__ h, const float* __restrict__ cw, const float* __restrict__ cb,
    const float* __restrict__ cg, const float* __restrict__ cbeta, float* __restrict__ g) {
  __shared__ float lcw[DD * 128];
  __shared__ float lcb[128], lcg[128], lcbt[128];
  __shared__ __attribute__((aligned(16))) float hb[4][DD][4];
  __shared__ float wmax[4][128];
  int tid = threadIdx.x;
  for (int i = tid; i < DD * 128; i += 256) lcw[i] = cw[i];
  if (tid < 128) { lcb[tid] = cb[tid]; lcg[tid] = cg[tid]; lcbt[tid] = cbeta[tid]; }
  __syncthreads();
  int w = tid >> 6, c = tid & 63;
  int b = blockIdx.x & 7;             // XCD-pinned batch
  int blk = blockIdx.x >> 3;          // 128 block-positions per batch
  int base = b * NN + blk * 32;
  float m0 = 0.0f, m1 = 0.0f;
  for (int it = 0; it < 2; ++it) {
    int p0 = base + (w * 2 + it) * 4;
#pragma unroll
    for (int i = 0; i < 4; i++) hb[w][c][i] = h[(size_t)(p0 + i) * 64 + c];
    float a0[4], a1[4];
#pragma unroll
    for (int i = 0; i < 4; i++) { a0[i] = lcb[c]; a1[i] = lcb[64 + c]; }
#pragma unroll 4
    for (int d = 0; d < DD; d++) {
      float w0 = lcw[d * 128 + c], w1 = lcw[d * 128 + 64 + c];
      float4 hv = *(const float4*)&hb[w][d][0];
      a0[0] = fmaf(hv.x, w0, a0[0]); a0[1] = fmaf(hv.y, w0, a0[1]);
      a0[2] = fmaf(hv.z, w0, a0[2]); a0[3] = fmaf(hv.w, w0, a0[3]);
      a1[0] = fmaf(hv.x, w1, a1[0]); a1[1] = fmaf(hv.y, w1, a1[1]);
      a1[2] = fmaf(hv.z, w1, a1[2]); a1[3] = fmaf(hv.w, w1, a1[3]);
    }
#pragma unroll
    for (int i = 0; i < 4; i++) {
      m0 = fmaxf(m0, fmaxf(0.0f, fmaf(lcg[c] * a0[i], BNRS, lcbt[c])));
      m1 = fmaxf(m1, fmaxf(0.0f, fmaf(lcg[64 + c] * a1[i], BNRS, lcbt[64 + c])));
    }
  }
  wmax[w][c] = m0; wmax[w][64 + c] = m1;
  __syncthreads();
  if (tid < 128) {
    float mm = fmaxf(fmaxf(wmax[0][tid], wmax[1][tid]), fmaxf(wmax[2][tid], wmax[3][tid]));
    atomicMax((int*)&g[b * 128 + tid], __float_as_int(mm));  // values >= 0
  }
}

// ---------------------------------------------------------------- final head (per batch)
__global__ __launch_bounds__(128) void head_kernel(
    const float* __restrict__ g,
    const float* __restrict__ f1w, const float* __restrict__ f1b,
    const float* __restrict__ b1g, const float* __restrict__ b1b,
    const float* __restrict__ f2w, const float* __restrict__ f2b,
    const float* __restrict__ b2g, const float* __restrict__ b2b,
    const float* __restrict__ f3w, const float* __restrict__ f3b,
    float* __restrict__ out) {
  __shared__ float gb[128], g1[128], g2[64];
  int b = blockIdx.x, t = threadIdx.x;
  gb[t] = g[b * 128 + t];
  __syncthreads();
  float a = f1b[t];
#pragma unroll 4
  for (int d = 0; d < 128; d++) a = fmaf(gb[d], f1w[d * 128 + t], a);
  g1[t] = fmaxf(0.0f, fmaf(b1g[t] * a, BNRS, b1b[t]));
  __syncthreads();
  if (t < 64) {
    float a2 = f2b[t];
#pragma unroll 4
    for (int j = 0; j < 128; j++) a2 = fmaf(g1[j], f2w[j * 64 + t], a2);
    g2[t] = fmaxf(0.0f, fmaf(b2g[t] * a2, BNRS, b2b[t]));
  }
  __syncthreads();
  if (t < NCLS) {
    float a3 = f3b[t];
#pragma unroll
    for (int d = 0; d < 64; d++) a3 = fmaf(g2[d], f3w[d * NCLS + t], a3);
    out[b * NCLS + t] = a3;
  }
}

extern "C" void kernel_launch(void* const* d_in, const int* in_sizes, int n_in,
                              void* d_out, int out_size, void* d_ws, size_t ws_size,
                              hipStream_t stream) {
  const float* x    = (const float*)d_in[0];
  const float* ew1  = (const float*)d_in[1];
  const float* eb1  = (const float*)d_in[2];
  const float* ew2  = (const float*)d_in[3];
  const float* eb2  = (const float*)d_in[4];
  const float* wq   = (const float*)d_in[5];
  const float* bq   = (const float*)d_in[6];
  const float* wk   = (const float*)d_in[7];
  const float* bk   = (const float*)d_in[8];
  const float* wv   = (const float*)d_in[9];
  const float* bv   = (const float*)d_in[10];
  const float* pw1  = (const float*)d_in[11];
  const float* pb1  = (const float*)d_in[12];
  const float* pw2  = (const float*)d_in[13];
  const float* pb2  = (const float*)d_in[14];
  const float* aw   = (const float*)d_in[15];
  const float* ab   = (const float*)d_in[16];
  const float* ow   = (const float*)d_in[17];
  const float* ob   = (const float*)d_in[18];
  const float* l1g  = (const float*)d_in[19];
  const float* l1b  = (const float*)d_in[20];
  const float* l2g  = (const float*)d_in[21];
  const float* l2b  = (const float*)d_in[22];
  const float* fw1  = (const float*)d_in[23];
  const float* fb1  = (const float*)d_in[24];
  const float* fw2  = (const float*)d_in[25];
  const float* fb2  = (const float*)d_in[26];
  const float* cw   = (const float*)d_in[27];
  const float* cb   = (const float*)d_in[28];
  const float* cg   = (const float*)d_in[29];
  const float* cbeta= (const float*)d_in[30];
  const float* f1w  = (const float*)d_in[31];
  const float* f1b  = (const float*)d_in[32];
  const float* b1g  = (const float*)d_in[33];
  const float* b1b  = (const float*)d_in[34];
  const float* f2w  = (const float*)d_in[35];
  const float* f2b  = (const float*)d_in[36];
  const float* b2g  = (const float*)d_in[37];
  const float* b2b  = (const float*)d_in[38];
  const float* f3w  = (const float*)d_in[39];
  const float* f3b  = (const float*)d_in[40];

  const size_t P = (size_t)BB * NN;       // 32768 points
  float* ws = (float*)d_ws;
  float* h = ws;                          // P*64
  float* q = h + P * 64;
  float* k = q + P * 64;
  float* v = k + P * 64;
  int* idx = (int*)(v + P * 64);          // P*8 ints
  float* g = (float*)(idx + P * 8);       // B*128
  float4* ppg = (float4*)(g + BB * 128);  // P float4 (aligned: offset is 16B-multiple)

  zero_kernel<<<1, BB * 128, 0, stream>>>(g);
  embed_kernel<<<(int)(P / 4), 256, 0, stream>>>(x, ew1, eb1, ew2, eb2, h);
  knn_prep_kernel<<<(int)(P / 256), 256, 0, stream>>>(x, ppg);
  knn_kernel<<<BB * (NN / QPB), 1024, 0, stream>>>(ppg, idx);
  for (int l = 0; l < 2; l++) {
    qkv_kernel<<<(int)(P / 8), 128, 0, stream>>>(h, wq + l * DD * DD, bq + l * DD,
                                                 wk + l * DD * DD, bk + l * DD,
                                                 wv + l * DD * DD, bv + l * DD, q, k, v);
    attn_ffn_kernel<<<(int)(P / 4), 128, 0, stream>>>(
        x, h, q, k, v, idx,
        pw1 + l * 3 * DD, pb1 + l * DD, pw2 + l * DD * DD, pb2 + l * DD,
        aw + l * DD, ab + l, ow + l * DD * DD, ob + l * DD,
        l1g + l * DD, l1b + l * DD,
        fw1 + l * DD * 2 * DD, fb1 + l * 2 * DD, fw2 + l * 2 * DD * DD, fb2 + l * DD,
        l2g + l * DD, l2b + l * DD);
  }
  cls_kernel<<<BB * 128, 256, 0, stream>>>(h, cw, cb, cg, cbeta, g);
  head_kernel<<<BB, 128, 0, stream>>>(g, f1w, f1b, b1g, b1b, f2w, f2b, b2g, b2b, f3w, f3b,
                                      (float*)d_out);
}

// Round 16
// 393.647 us; speedup vs baseline: 1.0345x; 1.0345x over previous
//
#include <hip/hip_runtime.h>
#include <cmath>

#define BB 8
#define NN 4096
#define DD 64
#define KK 8
#define NCLS 2

constexpr float LNEPS = 1e-5f;
constexpr float BNRS = 0.9999950000374994f;      // 1/sqrt(1+1e-5)
constexpr float INVSQRT2 = 0.70710678118654752440f;

// knn decomposition: 64 queries/block x 16 candidate-splits (one per wave)
#define QPB 64
#define SPLITS 16
#define SUBSET 64     // pass-1 subset per split (16*64 = 1024-point bound set)

__device__ __forceinline__ float wave_sum(float v) {
#pragma unroll
  for (int m = 32; m > 0; m >>= 1) v += __shfl_xor(v, m, 64);
  return v;
}

__device__ __forceinline__ float gelu_exact(float x) {
  return 0.5f * x * (1.0f + erff(x * INVSQRT2));
}

// identical in both knn passes -> bit-identical distances
__device__ __forceinline__ float dist2(float4 q, float4 p) {
  float dot = fmaf(q.x, p.x, fmaf(q.y, p.y, q.z * p.z));
  return fmaf(-2.0f, dot, q.w + p.w);
}

// ---------------------------------------------------------------- zero g
__global__ void zero_kernel(float* g) { g[threadIdx.x] = 0.0f; }

// ---------------------------------------------------------------- embed: h = relu(x@ew1+eb1)@ew2+eb2
__global__ __launch_bounds__(256) void embed_kernel(
    const float* __restrict__ x, const float* __restrict__ ew1, const float* __restrict__ eb1,
    const float* __restrict__ ew2, const float* __restrict__ eb2, float* __restrict__ h) {
  __shared__ float h1[4][DD];
  int w = threadIdx.x >> 6, c = threadIdx.x & 63;
  int pt = ((blockIdx.x & 7) << 12) + (blockIdx.x >> 3) * 4 + w;
  const float* xp = x + (size_t)pt * 3;
  float x0 = xp[0], x1 = xp[1], x2 = xp[2];
  float a = fmaf(x0, ew1[c], fmaf(x1, ew1[64 + c], fmaf(x2, ew1[128 + c], eb1[c])));
  h1[w][c] = fmaxf(a, 0.0f);
  float s = eb2[c];
#pragma unroll 8
  for (int d = 0; d < DD; d++) s = fmaf(h1[w][d], ew2[d * 64 + c], s);
  h[(size_t)pt * 64 + c] = s;
}

// ---------------------------------------------------------------- knn prep: ppg[b*N+j] = (x,y,z,|p|^2)
__global__ __launch_bounds__(256) void knn_prep_kernel(const float* __restrict__ x,
                                                       float4* __restrict__ ppg) {
  int i = ((blockIdx.x & 7) << 12) + (blockIdx.x >> 3) * 256 + threadIdx.x;
  float a0 = x[3 * i + 0], a1 = x[3 * i + 1], a2 = x[3 * i + 2];
  ppg[i] = make_float4(a0, a1, a2, a0 * a0 + a1 * a1 + a2 * a2);
}

// ---------------------------------------------------------------- knn: exact top-8 (stable ties), 2-pass
__global__ __launch_bounds__(1024) void knn_kernel(const float4* __restrict__ ppg,
                                                   int* __restrict__ idx) {
  __shared__ union {
    float v[SPLITS * 8][QPB];       // pass-1 value lists
    double k[SPLITS * 8][QPB];      // pass-2 key lists (64 KB)
  } mb;
  __shared__ float thrq[QPB];
  int b = blockIdx.x & 7;           // XCD-pinned batch
  int qbase = (blockIdx.x >> 3) * QPB;
  const float4* pb = ppg + (size_t)b * NN;
  int ql = threadIdx.x & 63;
  int sp = __builtin_amdgcn_readfirstlane(threadIdx.x >> 6);  // wave id = split id (SGPR)
  float4 qp = pb[qbase + ql];
  const float4* cp = pb + sp * (NN / SPLITS);                 // scalar base

  // ---- pass 1: branchless top-8 distances over SUBSET candidates
  float bd[8];
#pragma unroll
  for (int u = 0; u < 8; u++) bd[u] = INFINITY;
#pragma unroll 4
  for (int jj = 0; jj < SUBSET; ++jj) {
    float d2 = dist2(qp, cp[jj]);
#pragma unroll
    for (int u = 7; u > 0; --u) bd[u] = fminf(bd[u], fmaxf(bd[u - 1], d2));
    bd[0] = fminf(bd[0], d2);
  }
#pragma unroll
  for (int u = 0; u < 8; u++) mb.v[sp * 8 + u][ql] = bd[u];
  __syncthreads();

  // ---- U merge stage 1
  if (sp < 8) {
    float cd[8];
#pragma unroll
    for (int u = 0; u < 8; u++) cd[u] = INFINITY;
    int base = sp * 16;
#pragma unroll
    for (int e = 0; e < 16; e++) {
      float vv = mb.v[base + e][ql];
#pragma unroll
      for (int u = 7; u > 0; --u) cd[u] = fminf(cd[u], fmaxf(cd[u - 1], vv));
      cd[0] = fminf(cd[0], vv);
    }
#pragma unroll
    for (int u = 0; u < 8; u++) mb.v[base + u][ql] = cd[u];
  }
  __syncthreads();

  // ---- U merge stage 2
  if (sp == 0) {
    float cd[8];
#pragma unroll
    for (int u = 0; u < 8; u++) cd[u] = INFINITY;
    for (int m = 0; m < 8; m++) {
      for (int e = 0; e < 8; e++) {
        float vv = mb.v[m * 16 + e][ql];
        if (__all(vv >= cd[7])) break;
#pragma unroll
        for (int u = 7; u > 0; --u) cd[u] = fminf(cd[u], fmaxf(cd[u - 1], vv));
        cd[0] = fminf(cd[0], vv);
      }
    }
    thrq[ql] = cd[7];
  }
  __syncthreads();
  float U = thrq[ql];

  // ---- init key slots
#pragma unroll
  for (int u = 0; u < 8; u++) mb.k[sp * 8 + u][ql] = INFINITY;

  // ---- pass 2: FIFO-collect hits (d2<=U) per split; overflow -> replace-max
  int cnt = 0;
#pragma unroll 4
  for (int jj = 0; jj < NN / SPLITS; ++jj) {
    float d2 = dist2(qp, cp[jj]);
    if (d2 <= U) {
      double key = __hiloint2double(__float_as_int(d2), sp * (NN / SPLITS) + jj);
      if (cnt < 8) {
        mb.k[sp * 8 + cnt][ql] = key;
        cnt++;
      } else {
        double mx = mb.k[sp * 8 + 0][ql];
        int mi = 0;
#pragma unroll
        for (int u = 1; u < 8; u++) {
          double tv = mb.k[sp * 8 + u][ql];
          if (tv > mx) { mx = tv; mi = u; }
        }
        if (key < mx) mb.k[sp * 8 + mi][ql] = key;
      }
    }
  }
  __syncthreads();

  // ---- key merge stage 1 (network accepts unsorted input; output sorted)
  if (sp < 8) {
    double cd[8];
#pragma unroll
    for (int u = 0; u < 8; u++) cd[u] = INFINITY;
    int base = sp * 16;
#pragma unroll
    for (int e = 0; e < 16; e++) {
      double key = mb.k[base + e][ql];
#pragma unroll
      for (int u = 7; u > 0; --u) cd[u] = fmin(cd[u], fmax(cd[u - 1], key));
      cd[0] = fmin(cd[0], key);
    }
#pragma unroll
    for (int u = 0; u < 8; u++) mb.k[base + u][ql] = cd[u];
  }
  __syncthreads();

  // ---- key merge stage 2 + write
  if (sp == 0) {
    double cd[8];
#pragma unroll
    for (int u = 0; u < 8; u++) cd[u] = INFINITY;
    for (int m = 0; m < 8; m++) {
      for (int e = 0; e < 8; e++) {
        double key = mb.k[m * 16 + e][ql];
        if (__all(key >= cd[7])) break;
#pragma unroll
        for (int u = 7; u > 0; --u) cd[u] = fmin(cd[u], fmax(cd[u - 1], key));
        cd[0] = fmin(cd[0], key);
      }
    }
    int* op = idx + ((size_t)b * NN + qbase + ql) * 8;
#pragma unroll
    for (int u = 0; u < 8; u++) op[u] = __double2loint(cd[u]);
  }
}

// ---------------------------------------------------------------- qkv projection: 1-wave blocks, 4 points/wave
__global__ __launch_bounds__(64) void qkv_kernel(
    const float* __restrict__ h, const float* __restrict__ wq, const float* __restrict__ bq,
    const float* __restrict__ wk, const float* __restrict__ bk,
    const float* __restrict__ wv, const float* __restrict__ bv,
    float* __restrict__ q, float* __restrict__ k, float* __restrict__ v) {
  __shared__ __attribute__((aligned(16))) float hb[DD][4];
  int c = threadIdx.x;
  int b = blockIdx.x & 7, pos = blockIdx.x >> 3;   // 1024 positions per batch
  int p0 = (b << 12) + pos * 4;
#pragma unroll
  for (int i = 0; i < 4; i++) hb[c][i] = h[(size_t)(p0 + i) * 64 + c];
  float bqc = bq[c], bkc = bk[c], bvc = bv[c];
  float aq[4], ak[4], av[4];
#pragma unroll
  for (int i = 0; i < 4; i++) { aq[i] = bqc; ak[i] = bkc; av[i] = bvc; }
#pragma unroll 4
  for (int d = 0; d < DD; d++) {
    float wq_ = wq[d * 64 + c], wk_ = wk[d * 64 + c], wv_ = wv[d * 64 + c];
    float4 hh = *(const float4*)&hb[d][0];
    aq[0] = fmaf(hh.x, wq_, aq[0]); aq[1] = fmaf(hh.y, wq_, aq[1]);
    aq[2] = fmaf(hh.z, wq_, aq[2]); aq[3] = fmaf(hh.w, wq_, aq[3]);
    ak[0] = fmaf(hh.x, wk_, ak[0]); ak[1] = fmaf(hh.y, wk_, ak[1]);
    ak[2] = fmaf(hh.z, wk_, ak[2]); ak[3] = fmaf(hh.w, wk_, ak[3]);
    av[0] = fmaf(hh.x, wv_, av[0]); av[1] = fmaf(hh.y, wv_, av[1]);
    av[2] = fmaf(hh.z, wv_, av[2]); av[3] = fmaf(hh.w, wv_, av[3]);
  }
#pragma unroll
  for (int i = 0; i < 4; i++) {
    q[(size_t)(p0 + i) * 64 + c] = aq[i];
    k[(size_t)(p0 + i) * 64 + c] = ak[i];
    v[(size_t)(p0 + i) * 64 + c] = av[i];
  }
}

// ---------------------------------------------------------------- fused attention+ffn: 1-wave blocks, 4 points/wave
// Weight streams (pw2/ow/fw1/fw2) amortized over 4 points; LDS 9KB via union
// (h1b reused as tb/hb2 after pe2 -- same-wave in-order DS makes aliasing safe).
// h read (residual) and written for the SAME points only -> no cross-wave hazard.
__global__ __launch_bounds__(64) void attn_ffn_kernel(
    const float* __restrict__ x, float* h,
    const float* __restrict__ q, const float* __restrict__ kk, const float* __restrict__ vv,
    const int* __restrict__ idx,
    const float* __restrict__ pw1, const float* __restrict__ pb1,
    const float* __restrict__ pw2, const float* __restrict__ pb2,
    const float* __restrict__ aw, const float* __restrict__ ab,
    const float* __restrict__ ow, const float* __restrict__ ob,
    const float* __restrict__ l1g, const float* __restrict__ l1b,
    const float* __restrict__ fw1, const float* __restrict__ fb1,
    const float* __restrict__ fw2, const float* __restrict__ fb2,
    const float* __restrict__ l2g, const float* __restrict__ l2b) {
  __shared__ __attribute__((aligned(16))) union {
    float h1b[4][DD][8];                                     // 8KB (attn phase)
    struct { float tb[DD][4]; float hb2[128][4]; } f;        // 3KB (ffn phase)
  } su;
  __shared__ __attribute__((aligned(16))) float outb[4][DD]; // 1KB
  int c = threadIdx.x;
  int b = blockIdx.x & 7;                 // XCD-pinned batch
  int n0 = (blockIdx.x >> 3) * 4;         // 1024 block-positions per batch
  int p0 = (b << 12) + n0;
  const float* xb = x + (size_t)b * NN * 3;
  float w1c0 = pw1[c], w1c1 = pw1[64 + c], w1c2 = pw1[128 + c], b1c = pb1[c];
  float pb2c = pb2[c], lawc = aw[c], lobc = ob[c], g1c = l1g[c], bt1c = l1b[c];
  float lab = ab[0];
  float hs[4], qs[4];
#pragma unroll
  for (int i = 0; i < 4; i++) {
    hs[i] = h[(size_t)(p0 + i) * 64 + c];
    qs[i] = q[(size_t)(p0 + i) * 64 + c];
  }
  int nb[4][8];
#pragma unroll
  for (int pt = 0; pt < 4; ++pt)
#pragma unroll
    for (int u = 0; u < 8; u++) nb[pt][u] = idx[(size_t)(p0 + pt) * 8 + u];
  // ---- prefetch all k/v gather rows; latency hides under pe1+pe2 compute
  float kv[4][8], vg[4][8];
#pragma unroll
  for (int pt = 0; pt < 4; ++pt)
#pragma unroll
    for (int u = 0; u < 8; u++) {
      kv[pt][u] = kk[((size_t)(b << 12) + nb[pt][u]) * 64 + c];
      vg[pt][u] = vv[((size_t)(b << 12) + nb[pt][u]) * 64 + c];
    }
  // ---- pe1 -> LDS
#pragma unroll
  for (int pt = 0; pt < 4; ++pt) {
    int n = n0 + pt;
    float px0 = xb[n * 3 + 0], px1 = xb[n * 3 + 1], px2 = xb[n * 3 + 2];
    float h1v[8];
#pragma unroll
    for (int u = 0; u < 8; u++) {
      int m = nb[pt][u];
      float d0 = px0 - xb[m * 3 + 0], d1 = px1 - xb[m * 3 + 1], d2 = px2 - xb[m * 3 + 2];
      h1v[u] = fmaxf(fmaf(d0, w1c0, fmaf(d1, w1c1, fmaf(d2, w1c2, b1c))), 0.0f);
    }
    *(float4*)&su.h1b[pt][c][0] = make_float4(h1v[0], h1v[1], h1v[2], h1v[3]);
    *(float4*)&su.h1b[pt][c][4] = make_float4(h1v[4], h1v[5], h1v[6], h1v[7]);
  }
  // ---- pe2: one pw2 load feeds 32 FMAs
  float acc[4][8];
#pragma unroll
  for (int pt = 0; pt < 4; ++pt)
#pragma unroll
    for (int u = 0; u < 8; u++) acc[pt][u] = pb2c;
#pragma unroll 2
  for (int d = 0; d < DD; d++) {
    float wv_ = pw2[d * 64 + c];
#pragma unroll
    for (int pt = 0; pt < 4; ++pt) {
      float4 lo = *(const float4*)&su.h1b[pt][d][0];
      float4 hi = *(const float4*)&su.h1b[pt][d][4];
      acc[pt][0] = fmaf(lo.x, wv_, acc[pt][0]); acc[pt][1] = fmaf(lo.y, wv_, acc[pt][1]);
      acc[pt][2] = fmaf(lo.z, wv_, acc[pt][2]); acc[pt][3] = fmaf(lo.w, wv_, acc[pt][3]);
      acc[pt][4] = fmaf(hi.x, wv_, acc[pt][4]); acc[pt][5] = fmaf(hi.y, wv_, acc[pt][5]);
      acc[pt][6] = fmaf(hi.z, wv_, acc[pt][6]); acc[pt][7] = fmaf(hi.w, wv_, acc[pt][7]);
    }
  }
  // ---- logits (kv regs die here), softmax, out
  float out[4];
#pragma unroll
  for (int pt = 0; pt < 4; ++pt) {
    float lg[8];
#pragma unroll
    for (int u = 0; u < 8; u++)
      lg[u] = wave_sum((qs[pt] - kv[pt][u] + acc[pt][u]) * lawc) + lab;
    float mx = lg[0];
#pragma unroll
    for (int u = 1; u < 8; u++) mx = fmaxf(mx, lg[u]);
    float ssum = 0.0f;
#pragma unroll
    for (int u = 0; u < 8; u++) { lg[u] = expf(lg[u] - mx); ssum += lg[u]; }
    float inv = 1.0f / ssum;
    float o = 0.0f;
#pragma unroll
    for (int u = 0; u < 8; u++) o = fmaf(lg[u] * inv, vg[pt][u] + acc[pt][u], o);
    out[pt] = o;
    outb[pt][c] = o;
  }
  // ---- out @ ow + ob (one ow load feeds 4 FMAs... 4 points x 4-wide)
  float at[4];
#pragma unroll
  for (int pt = 0; pt < 4; ++pt) at[pt] = lobc;
#pragma unroll 4
  for (int d = 0; d < DD; d += 4) {
    float wa = ow[(d + 0) * 64 + c], wb = ow[(d + 1) * 64 + c];
    float wc = ow[(d + 2) * 64 + c], wd = ow[(d + 3) * 64 + c];
#pragma unroll
    for (int pt = 0; pt < 4; ++pt) {
      float4 ov = *(const float4*)&outb[pt][d];
      at[pt] = fmaf(ov.x, wa, at[pt]); at[pt] = fmaf(ov.y, wb, at[pt]);
      at[pt] = fmaf(ov.z, wc, at[pt]); at[pt] = fmaf(ov.w, wd, at[pt]);
    }
  }
  // ---- ln1 -> t (regs) ; also stash to LDS tb (aliases h1b -- pe2 done)
  float tv[4];
#pragma unroll
  for (int pt = 0; pt < 4; ++pt) {
    float res = at[pt] + hs[pt];
    float mean = wave_sum(res) * (1.0f / 64.0f);
    float dv = res - mean;
    float var = wave_sum(dv * dv) * (1.0f / 64.0f);
    float ivr = 1.0f / sqrtf(var + LNEPS);
    tv[pt] = fmaf(g1c, dv * ivr, bt1c);
    su.f.tb[c][pt] = tv[pt];
  }
  // ---- ffn fc1
  float fb1a = fb1[c], fb1b = fb1[64 + c];
  float hA[4], hB[4];
#pragma unroll
  for (int i = 0; i < 4; i++) { hA[i] = fb1a; hB[i] = fb1b; }
#pragma unroll 4
  for (int d = 0; d < DD; d++) {
    float w0 = fw1[d * 128 + c], w1 = fw1[d * 128 + 64 + c];
    float4 yv = *(const float4*)&su.f.tb[d][0];
    hA[0] = fmaf(yv.x, w0, hA[0]); hA[1] = fmaf(yv.y, w0, hA[1]);
    hA[2] = fmaf(yv.z, w0, hA[2]); hA[3] = fmaf(yv.w, w0, hA[3]);
    hB[0] = fmaf(yv.x, w1, hB[0]); hB[1] = fmaf(yv.y, w1, hB[1]);
    hB[2] = fmaf(yv.z, w1, hB[2]); hB[3] = fmaf(yv.w, w1, hB[3]);
  }
#pragma unroll
  for (int i = 0; i < 4; i++) {
    hA[i] = gelu_exact(hA[i]); hB[i] = gelu_exact(hB[i]);
    su.f.hb2[c][i] = hA[i]; su.f.hb2[64 + c][i] = hB[i];
  }
  // ---- ffn fc2
  float fb2c = fb2[c], g2c = l2g[c], bt2c = l2b[c];
  float o[4];
#pragma unroll
  for (int i = 0; i < 4; i++) o[i] = fb2c;
#pragma unroll 4
  for (int j = 0; j < 128; j++) {
    float wv_ = fw2[j * 64 + c];
    float4 hv = *(const float4*)&su.f.hb2[j][0];
    o[0] = fmaf(hv.x, wv_, o[0]); o[1] = fmaf(hv.y, wv_, o[1]);
    o[2] = fmaf(hv.z, wv_, o[2]); o[3] = fmaf(hv.w, wv_, o[3]);
  }
  // ---- ln2 -> h
#pragma unroll
  for (int pt = 0; pt < 4; ++pt) {
    float r = tv[pt] + o[pt];
    float mean = wave_sum(r) * (1.0f / 64.0f);
    float dv = r - mean;
    float var = wave_sum(dv * dv) * (1.0f / 64.0f);
    float ivr = 1.0f / sqrtf(var + LNEPS);
    h[(size_t)(p0 + pt) * 64 + c] = fmaf(g2c, dv * ivr, bt2c);
  }
}

// ---------------------------------------------------------------- classifier proj + blockwise max-pool (XCD-pinned)
__global__ __launch_bounds__(256) void cls_kernel(
    const float* __restrict__ h, const float* __restrict__ cw, const float* __restrict__ cb,
    const float* __restrict__ cg, const float* __restrict__ cbeta, float* __restrict__ g) {
  __shared__ float lcw[DD * 128];
  __shared__ float lcb[128], lcg[128], lcbt[128];
  __shared__ __attribute__((aligned(16))) float hb[4][DD][4];
  __shared__ float wmax[4][128];
  int tid = threadIdx.x;
  for (int i = tid; i < DD * 128; i += 256) lcw[i] = cw[i];
  if (tid < 128) { lcb[tid] = cb[tid]; lcg[tid] = cg[tid]; lcbt[tid] = cbeta[tid]; }
  __syncthreads();
  int w = tid >> 6, c = tid & 63;
  int b = blockIdx.x & 7;             // XCD-pinned batch
  int blk = blockIdx.x >> 3;          // 128 block-positions per batch
  int base = b * NN + blk * 32;
  float m0 = 0.0f, m1 = 0.0f;
  for (int it = 0; it < 2; ++it) {
    int p0 = base + (w * 2 + it) * 4;
#pragma unroll
    for (int i = 0; i < 4; i++) hb[w][c][i] = h[(size_t)(p0 + i) * 64 + c];
    float a0[4], a1[4];
#pragma unroll
    for (int i = 0; i < 4; i++) { a0[i] = lcb[c]; a1[i] = lcb[64 + c]; }
#pragma unroll 4
    for (int d = 0; d < DD; d++) {
      float w0 = lcw[d * 128 + c], w1 = lcw[d * 128 + 64 + c];
      float4 hv = *(const float4*)&hb[w][d][0];
      a0[0] = fmaf(hv.x, w0, a0[0]); a0[1] = fmaf(hv.y, w0, a0[1]);
      a0[2] = fmaf(hv.z, w0, a0[2]); a0[3] = fmaf(hv.w, w0, a0[3]);
      a1[0] = fmaf(hv.x, w1, a1[0]); a1[1] = fmaf(hv.y, w1, a1[1]);
      a1[2] = fmaf(hv.z, w1, a1[2]); a1[3] = fmaf(hv.w, w1, a1[3]);
    }
#pragma unroll
    for (int i = 0; i < 4; i++) {
      m0 = fmaxf(m0, fmaxf(0.0f, fmaf(lcg[c] * a0[i], BNRS, lcbt[c])));
      m1 = fmaxf(m1, fmaxf(0.0f, fmaf(lcg[64 + c] * a1[i], BNRS, lcbt[64 + c])));
    }
  }
  wmax[w][c] = m0; wmax[w][64 + c] = m1;
  __syncthreads();
  if (tid < 128) {
    float mm = fmaxf(fmaxf(wmax[0][tid], wmax[1][tid]), fmaxf(wmax[2][tid], wmax[3][tid]));
    atomicMax((int*)&g[b * 128 + tid], __float_as_int(mm));  // values >= 0
  }
}

// ---------------------------------------------------------------- final head (per batch)
__global__ __launch_bounds__(128) void head_kernel(
    const float* __restrict__ g,
    const float* __restrict__ f1w, const float* __restrict__ f1b,
    const float* __restrict__ b1g, const float* __restrict__ b1b,
    const float* __restrict__ f2w, const float* __restrict__ f2b,
    const float* __restrict__ b2g, const float* __restrict__ b2b,
    const float* __restrict__ f3w, const float* __restrict__ f3b,
    float* __restrict__ out) {
  __shared__ float gb[128], g1[128], g2[64];
  int b = blockIdx.x, t = threadIdx.x;
  gb[t] = g[b * 128 + t];
  __syncthreads();
  float a = f1b[t];
#pragma unroll 4
  for (int d = 0; d < 128; d++) a = fmaf(gb[d], f1w[d * 128 + t], a);
  g1[t] = fmaxf(0.0f, fmaf(b1g[t] * a, BNRS, b1b[t]));
  __syncthreads();
  if (t < 64) {
    float a2 = f2b[t];
#pragma unroll 4
    for (int j = 0; j < 128; j++) a2 = fmaf(g1[j], f2w[j * 64 + t], a2);
    g2[t] = fmaxf(0.0f, fmaf(b2g[t] * a2, BNRS, b2b[t]));
  }
  __syncthreads();
  if (t < NCLS) {
    float a3 = f3b[t];
#pragma unroll
    for (int d = 0; d < 64; d++) a3 = fmaf(g2[d], f3w[d * NCLS + t], a3);
    out[b * NCLS + t] = a3;
  }
}

extern "C" void kernel_launch(void* const* d_in, const int* in_sizes, int n_in,
                              void* d_out, int out_size, void* d_ws, size_t ws_size,
                              hipStream_t stream) {
  const float* x    = (const float*)d_in[0];
  const float* ew1  = (const float*)d_in[1];
  const float* eb1  = (const float*)d_in[2];
  const float* ew2  = (const float*)d_in[3];
  const float* eb2  = (const float*)d_in[4];
  const float* wq   = (const float*)d_in[5];
  const float* bq   = (const float*)d_in[6];
  const float* wk   = (const float*)d_in[7];
  const float* bk   = (const float*)d_in[8];
  const float* wv   = (const float*)d_in[9];
  const float* bv   = (const float*)d_in[10];
  const float* pw1  = (const float*)d_in[11];
  const float* pb1  = (const float*)d_in[12];
  const float* pw2  = (const float*)d_in[13];
  const float* pb2  = (const float*)d_in[14];
  const float* aw   = (const float*)d_in[15];
  const float* ab   = (const float*)d_in[16];
  const float* ow   = (const float*)d_in[17];
  const float* ob   = (const float*)d_in[18];
  const float* l1g  = (const float*)d_in[19];
  const float* l1b  = (const float*)d_in[20];
  const float* l2g  = (const float*)d_in[21];
  const float* l2b  = (const float*)d_in[22];
  const float* fw1  = (const float*)d_in[23];
  const float* fb1  = (const float*)d_in[24];
  const float* fw2  = (const float*)d_in[25];
  const float* fb2  = (const float*)d_in[26];
  const float* cw   = (const float*)d_in[27];
  const float* cb   = (const float*)d_in[28];
  const float* cg   = (const float*)d_in[29];
  const float* cbeta= (const float*)d_in[30];
  const float* f1w  = (const float*)d_in[31];
  const float* f1b  = (const float*)d_in[32];
  const float* b1g  = (const float*)d_in[33];
  const float* b1b  = (const float*)d_in[34];
  const float* f2w  = (const float*)d_in[35];
  const float* f2b  = (const float*)d_in[36];
  const float* b2g  = (const float*)d_in[37];
  const float* b2b  = (const float*)d_in[38];
  const float* f3w  = (const float*)d_in[39];
  const float* f3b  = (const float*)d_in[40];

  const size_t P = (size_t)BB * NN;       // 32768 points
  float* ws = (float*)d_ws;
  float* h = ws;                          // P*64
  float* q = h + P * 64;
  float* k = q + P * 64;
  float* v = k + P * 64;
  int* idx = (int*)(v + P * 64);          // P*8 ints
  float* g = (float*)(idx + P * 8);       // B*128
  float4* ppg = (float4*)(g + BB * 128);  // P float4 (aligned: offset is 16B-multiple)

  zero_kernel<<<1, BB * 128, 0, stream>>>(g);
  embed_kernel<<<(int)(P / 4), 256, 0, stream>>>(x, ew1, eb1, ew2, eb2, h);
  knn_prep_kernel<<<(int)(P / 256), 256, 0, stream>>>(x, ppg);
  knn_kernel<<<BB * (NN / QPB), 1024, 0, stream>>>(ppg, idx);
  for (int l = 0; l < 2; l++) {
    qkv_kernel<<<(int)(P / 4), 64, 0, stream>>>(h, wq + l * DD * DD, bq + l * DD,
                                                wk + l * DD * DD, bk + l * DD,
                                                wv + l * DD * DD, bv + l * DD, q, k, v);
    attn_ffn_kernel<<<(int)(P / 4), 64, 0, stream>>>(
        x, h, q, k, v, idx,
        pw1 + l * 3 * DD, pb1 + l * DD, pw2 + l * DD * DD, pb2 + l * DD,
        aw + l * DD, ab + l, ow + l * DD * DD, ob + l * DD,
        l1g + l * DD, l1b + l * DD,
        fw1 + l * DD * 2 * DD, fb1 + l * 2 * DD, fw2 + l * 2 * DD * DD, fb2 + l * DD,
        l2g + l * DD, l2b + l * DD);
  }
  cls_kernel<<<BB * 128, 256, 0, stream>>>(h, cw, cb, cg, cbeta, g);
  head_kernel<<<BB, 128, 0, stream>>>(g, f1w, f1b, b1g, b1b, f2w, f2b, b2g, b2b, f3w, f3b,
                                      (float*)d_out);
}

// Round 17
// 367.025 us; speedup vs baseline: 1.1096x; 1.0725x over previous
//
#include <hip/hip_runtime.h>
#include <cmath>

#define BB 8
#define NN 4096
#define DD 64
#define KK 8
#define NCLS 2

constexpr float LNEPS = 1e-5f;
constexpr float BNRS = 0.9999950000374994f;      // 1/sqrt(1+1e-5)
constexpr float INVSQRT2 = 0.70710678118654752440f;

// knn decomposition: 64 queries/block x 16 candidate-splits (one per wave)
#define QPB 64
#define SPLITS 16
#define SUBSET 64     // pass-1 subset per split (16*64 = 1024-point bound set)

__device__ __forceinline__ float wave_sum(float v) {
#pragma unroll
  for (int m = 32; m > 0; m >>= 1) v += __shfl_xor(v, m, 64);
  return v;
}

__device__ __forceinline__ float gelu_exact(float x) {
  return 0.5f * x * (1.0f + erff(x * INVSQRT2));
}

// identical in both knn passes -> bit-identical distances
__device__ __forceinline__ float dist2(float4 q, float4 p) {
  float dot = fmaf(q.x, p.x, fmaf(q.y, p.y, q.z * p.z));
  return fmaf(-2.0f, dot, q.w + p.w);
}

// ---------------------------------------------------------------- zero g
__global__ void zero_kernel(float* g) { g[threadIdx.x] = 0.0f; }

// ---------------------------------------------------------------- embed: h = relu(x@ew1+eb1)@ew2+eb2
__global__ __launch_bounds__(256) void embed_kernel(
    const float* __restrict__ x, const float* __restrict__ ew1, const float* __restrict__ eb1,
    const float* __restrict__ ew2, const float* __restrict__ eb2, float* __restrict__ h) {
  __shared__ float h1[4][DD];
  int w = threadIdx.x >> 6, c = threadIdx.x & 63;
  int pt = ((blockIdx.x & 7) << 12) + (blockIdx.x >> 3) * 4 + w;
  const float* xp = x + (size_t)pt * 3;
  float x0 = xp[0], x1 = xp[1], x2 = xp[2];
  float a = fmaf(x0, ew1[c], fmaf(x1, ew1[64 + c], fmaf(x2, ew1[128 + c], eb1[c])));
  h1[w][c] = fmaxf(a, 0.0f);
  float s = eb2[c];
#pragma unroll 8
  for (int d = 0; d < DD; d++) s = fmaf(h1[w][d], ew2[d * 64 + c], s);
  h[(size_t)pt * 64 + c] = s;
}

// ---------------------------------------------------------------- knn prep: ppg[b*N+j] = (x,y,z,|p|^2)
__global__ __launch_bounds__(256) void knn_prep_kernel(const float* __restrict__ x,
                                                       float4* __restrict__ ppg) {
  int i = ((blockIdx.x & 7) << 12) + (blockIdx.x >> 3) * 256 + threadIdx.x;
  float a0 = x[3 * i + 0], a1 = x[3 * i + 1], a2 = x[3 * i + 2];
  ppg[i] = make_float4(a0, a1, a2, a0 * a0 + a1 * a1 + a2 * a2);
}

// ---------------------------------------------------------------- knn: exact top-8 (stable ties), 2-pass
// Pass-2 hit path: FIFO append to LDS; overflow (>8 hits/split, P~2e-4):
// replace-max-if-smaller keeps the split's 8 smallest hits -> provably exact.
__global__ __launch_bounds__(1024) void knn_kernel(const float4* __restrict__ ppg,
                                                   int* __restrict__ idx) {
  __shared__ union {
    float v[SPLITS * 8][QPB];       // pass-1 value lists
    double k[SPLITS * 8][QPB];      // pass-2 key lists (64 KB)
  } mb;
  __shared__ float thrq[QPB];
  int b = blockIdx.x & 7;           // XCD-pinned batch
  int qbase = (blockIdx.x >> 3) * QPB;
  const float4* pb = ppg + (size_t)b * NN;
  int ql = threadIdx.x & 63;
  int sp = __builtin_amdgcn_readfirstlane(threadIdx.x >> 6);  // wave id = split id (SGPR)
  float4 qp = pb[qbase + ql];
  const float4* cp = pb + sp * (NN / SPLITS);                 // scalar base

  // ---- pass 1: branchless top-8 distances over SUBSET candidates
  float bd[8];
#pragma unroll
  for (int u = 0; u < 8; u++) bd[u] = INFINITY;
#pragma unroll 4
  for (int jj = 0; jj < SUBSET; ++jj) {
    float d2 = dist2(qp, cp[jj]);
#pragma unroll
    for (int u = 7; u > 0; --u) bd[u] = fminf(bd[u], fmaxf(bd[u - 1], d2));
    bd[0] = fminf(bd[0], d2);
  }
#pragma unroll
  for (int u = 0; u < 8; u++) mb.v[sp * 8 + u][ql] = bd[u];
  __syncthreads();

  // ---- U merge stage 1
  if (sp < 8) {
    float cd[8];
#pragma unroll
    for (int u = 0; u < 8; u++) cd[u] = INFINITY;
    int base = sp * 16;
#pragma unroll
    for (int e = 0; e < 16; e++) {
      float vv = mb.v[base + e][ql];
#pragma unroll
      for (int u = 7; u > 0; --u) cd[u] = fminf(cd[u], fmaxf(cd[u - 1], vv));
      cd[0] = fminf(cd[0], vv);
    }
#pragma unroll
    for (int u = 0; u < 8; u++) mb.v[base + u][ql] = cd[u];
  }
  __syncthreads();

  // ---- U merge stage 2
  if (sp == 0) {
    float cd[8];
#pragma unroll
    for (int u = 0; u < 8; u++) cd[u] = INFINITY;
    for (int m = 0; m < 8; m++) {
      for (int e = 0; e < 8; e++) {
        float vv = mb.v[m * 16 + e][ql];
        if (__all(vv >= cd[7])) break;
#pragma unroll
        for (int u = 7; u > 0; --u) cd[u] = fminf(cd[u], fmaxf(cd[u - 1], vv));
        cd[0] = fminf(cd[0], vv);
      }
    }
    thrq[ql] = cd[7];
  }
  __syncthreads();
  float U = thrq[ql];

  // ---- init key slots
#pragma unroll
  for (int u = 0; u < 8; u++) mb.k[sp * 8 + u][ql] = INFINITY;

  // ---- pass 2: FIFO-collect hits (d2<=U) per split; overflow -> replace-max
  int cnt = 0;
#pragma unroll 4
  for (int jj = 0; jj < NN / SPLITS; ++jj) {
    float d2 = dist2(qp, cp[jj]);
    if (d2 <= U) {
      double key = __hiloint2double(__float_as_int(d2), sp * (NN / SPLITS) + jj);
      if (cnt < 8) {
        mb.k[sp * 8 + cnt][ql] = key;
        cnt++;
      } else {
        double mx = mb.k[sp * 8 + 0][ql];
        int mi = 0;
#pragma unroll
        for (int u = 1; u < 8; u++) {
          double tv = mb.k[sp * 8 + u][ql];
          if (tv > mx) { mx = tv; mi = u; }
        }
        if (key < mx) mb.k[sp * 8 + mi][ql] = key;
      }
    }
  }
  __syncthreads();

  // ---- key merge stage 1 (network accepts unsorted input; output sorted)
  if (sp < 8) {
    double cd[8];
#pragma unroll
    for (int u = 0; u < 8; u++) cd[u] = INFINITY;
    int base = sp * 16;
#pragma unroll
    for (int e = 0; e < 16; e++) {
      double key = mb.k[base + e][ql];
#pragma unroll
      for (int u = 7; u > 0; --u) cd[u] = fmin(cd[u], fmax(cd[u - 1], key));
      cd[0] = fmin(cd[0], key);
    }
#pragma unroll
    for (int u = 0; u < 8; u++) mb.k[base + u][ql] = cd[u];
  }
  __syncthreads();

  // ---- key merge stage 2 + write (stage-1 outputs sorted -> __all-break ok)
  if (sp == 0) {
    double cd[8];
#pragma unroll
    for (int u = 0; u < 8; u++) cd[u] = INFINITY;
    for (int m = 0; m < 8; m++) {
      for (int e = 0; e < 8; e++) {
        double key = mb.k[m * 16 + e][ql];
        if (__all(key >= cd[7])) break;
#pragma unroll
        for (int u = 7; u > 0; --u) cd[u] = fmin(cd[u], fmax(cd[u - 1], key));
        cd[0] = fmin(cd[0], key);
      }
    }
    int* op = idx + ((size_t)b * NN + qbase + ql) * 8;
#pragma unroll
    for (int u = 0; u < 8; u++) op[u] = __double2loint(cd[u]);
  }
}

// ---------------------------------------------------------------- qkv projection: 1-wave blocks, 4 points/wave
__global__ __launch_bounds__(64) void qkv_kernel(
    const float* __restrict__ h, const float* __restrict__ wq, const float* __restrict__ bq,
    const float* __restrict__ wk, const float* __restrict__ bk,
    const float* __restrict__ wv, const float* __restrict__ bv,
    float* __restrict__ q, float* __restrict__ k, float* __restrict__ v) {
  __shared__ __attribute__((aligned(16))) float hb[DD][4];
  int c = threadIdx.x;
  int b = blockIdx.x & 7, pos = blockIdx.x >> 3;   // 1024 positions per batch
  int p0 = (b << 12) + pos * 4;
#pragma unroll
  for (int i = 0; i < 4; i++) hb[c][i] = h[(size_t)(p0 + i) * 64 + c];
  float bqc = bq[c], bkc = bk[c], bvc = bv[c];
  float aq[4], ak[4], av[4];
#pragma unroll
  for (int i = 0; i < 4; i++) { aq[i] = bqc; ak[i] = bkc; av[i] = bvc; }
#pragma unroll 4
  for (int d = 0; d < DD; d++) {
    float wq_ = wq[d * 64 + c], wk_ = wk[d * 64 + c], wv_ = wv[d * 64 + c];
    float4 hh = *(const float4*)&hb[d][0];
    aq[0] = fmaf(hh.x, wq_, aq[0]); aq[1] = fmaf(hh.y, wq_, aq[1]);
    aq[2] = fmaf(hh.z, wq_, aq[2]); aq[3] = fmaf(hh.w, wq_, aq[3]);
    ak[0] = fmaf(hh.x, wk_, ak[0]); ak[1] = fmaf(hh.y, wk_, ak[1]);
    ak[2] = fmaf(hh.z, wk_, ak[2]); ak[3] = fmaf(hh.w, wk_, ak[3]);
    av[0] = fmaf(hh.x, wv_, av[0]); av[1] = fmaf(hh.y, wv_, av[1]);
    av[2] = fmaf(hh.z, wv_, av[2]); av[3] = fmaf(hh.w, wv_, av[3]);
  }
#pragma unroll
  for (int i = 0; i < 4; i++) {
    q[(size_t)(p0 + i) * 64 + c] = aq[i];
    k[(size_t)(p0 + i) * 64 + c] = ak[i];
    v[(size_t)(p0 + i) * 64 + c] = av[i];
  }
}

// ---------------------------------------------------------------- fused attention+ffn: 1-wave blocks, 2 points/wave
// attn -> t (registers) -> ffn -> h, all point-local after the k/v gathers.
// h is read (residual) and written for the SAME points only -> no cross-wave hazard.
__global__ __launch_bounds__(64) void attn_ffn_kernel(
    const float* __restrict__ x, float* h,
    const float* __restrict__ q, const float* __restrict__ kk, const float* __restrict__ vv,
    const int* __restrict__ idx,
    const float* __restrict__ pw1, const float* __restrict__ pb1,
    const float* __restrict__ pw2, const float* __restrict__ pb2,
    const float* __restrict__ aw, const float* __restrict__ ab,
    const float* __restrict__ ow, const float* __restrict__ ob,
    const float* __restrict__ l1g, const float* __restrict__ l1b,
    const float* __restrict__ fw1, const float* __restrict__ fb1,
    const float* __restrict__ fw2, const float* __restrict__ fb2,
    const float* __restrict__ l2g, const float* __restrict__ l2b) {
  __shared__ __attribute__((aligned(16))) float h1b[2][DD][8];   // 4KB
  __shared__ __attribute__((aligned(16))) float outb[2][DD];     // 0.5KB
  __shared__ __attribute__((aligned(8)))  float tb[DD][2];       // 0.5KB
  __shared__ __attribute__((aligned(8)))  float hb2[128][2];     // 1KB
  int c = threadIdx.x;
  int b = blockIdx.x & 7;                 // XCD-pinned batch
  int n0 = (blockIdx.x >> 3) * 2;         // 2048 positions per batch
  int p0 = (b << 12) + n0;
  const float* xb = x + (size_t)b * NN * 3;
  float w1c0 = pw1[c], w1c1 = pw1[64 + c], w1c2 = pw1[128 + c], b1c = pb1[c];
  float pb2c = pb2[c], lawc = aw[c], lobc = ob[c], g1c = l1g[c], bt1c = l1b[c];
  float lab = ab[0];
  float hs0 = h[(size_t)p0 * 64 + c], hs1 = h[(size_t)(p0 + 1) * 64 + c];
  float qs0 = q[(size_t)p0 * 64 + c], qs1 = q[(size_t)(p0 + 1) * 64 + c];
  int nb[2][8];
#pragma unroll
  for (int u = 0; u < 8; u++) {
    nb[0][u] = idx[(size_t)p0 * 8 + u];
    nb[1][u] = idx[(size_t)(p0 + 1) * 8 + u];
  }
  // ---- prefetch all k/v gather rows NOW; latency hides under pe1+pe2 compute
  float kv0[8], kv1[8], vg0[8], vg1[8];
#pragma unroll
  for (int u = 0; u < 8; u++) {
    kv0[u] = kk[((size_t)(b << 12) + nb[0][u]) * 64 + c];
    kv1[u] = kk[((size_t)(b << 12) + nb[1][u]) * 64 + c];
    vg0[u] = vv[((size_t)(b << 12) + nb[0][u]) * 64 + c];
    vg1[u] = vv[((size_t)(b << 12) + nb[1][u]) * 64 + c];
  }
#pragma unroll
  for (int pt = 0; pt < 2; ++pt) {
    int n = n0 + pt;
    float px0 = xb[n * 3 + 0], px1 = xb[n * 3 + 1], px2 = xb[n * 3 + 2];
    float h1v[8];
#pragma unroll
    for (int u = 0; u < 8; u++) {
      int m = nb[pt][u];
      float d0 = px0 - xb[m * 3 + 0], d1 = px1 - xb[m * 3 + 1], d2 = px2 - xb[m * 3 + 2];
      h1v[u] = fmaxf(fmaf(d0, w1c0, fmaf(d1, w1c1, fmaf(d2, w1c2, b1c))), 0.0f);
    }
    *(float4*)&h1b[pt][c][0] = make_float4(h1v[0], h1v[1], h1v[2], h1v[3]);
    *(float4*)&h1b[pt][c][4] = make_float4(h1v[4], h1v[5], h1v[6], h1v[7]);
  }
  float acc0[8], acc1[8];
#pragma unroll
  for (int u = 0; u < 8; u++) { acc0[u] = pb2c; acc1[u] = pb2c; }
#pragma unroll 2
  for (int d = 0; d < DD; d++) {
    float wv_ = pw2[d * 64 + c];
    float4 a0 = *(const float4*)&h1b[0][d][0];
    float4 b0 = *(const float4*)&h1b[0][d][4];
    float4 a1 = *(const float4*)&h1b[1][d][0];
    float4 b1 = *(const float4*)&h1b[1][d][4];
    acc0[0] = fmaf(a0.x, wv_, acc0[0]); acc0[1] = fmaf(a0.y, wv_, acc0[1]);
    acc0[2] = fmaf(a0.z, wv_, acc0[2]); acc0[3] = fmaf(a0.w, wv_, acc0[3]);
    acc0[4] = fmaf(b0.x, wv_, acc0[4]); acc0[5] = fmaf(b0.y, wv_, acc0[5]);
    acc0[6] = fmaf(b0.z, wv_, acc0[6]); acc0[7] = fmaf(b0.w, wv_, acc0[7]);
    acc1[0] = fmaf(a1.x, wv_, acc1[0]); acc1[1] = fmaf(a1.y, wv_, acc1[1]);
    acc1[2] = fmaf(a1.z, wv_, acc1[2]); acc1[3] = fmaf(a1.w, wv_, acc1[3]);
    acc1[4] = fmaf(b1.x, wv_, acc1[4]); acc1[5] = fmaf(b1.y, wv_, acc1[5]);
    acc1[6] = fmaf(b1.z, wv_, acc1[6]); acc1[7] = fmaf(b1.w, wv_, acc1[7]);
  }
  float lg0[8], lg1[8];
#pragma unroll
  for (int u = 0; u < 8; u++) {
    lg0[u] = wave_sum((qs0 - kv0[u] + acc0[u]) * lawc) + lab;
    lg1[u] = wave_sum((qs1 - kv1[u] + acc1[u]) * lawc) + lab;
  }
  float mx0 = lg0[0], mx1 = lg1[0];
#pragma unroll
  for (int u = 1; u < 8; u++) { mx0 = fmaxf(mx0, lg0[u]); mx1 = fmaxf(mx1, lg1[u]); }
  float s0 = 0.0f, s1 = 0.0f;
#pragma unroll
  for (int u = 0; u < 8; u++) {
    lg0[u] = expf(lg0[u] - mx0); s0 += lg0[u];
    lg1[u] = expf(lg1[u] - mx1); s1 += lg1[u];
  }
  float i0 = 1.0f / s0, i1 = 1.0f / s1;
  float out0 = 0.0f, out1 = 0.0f;
#pragma unroll
  for (int u = 0; u < 8; u++) {
    out0 = fmaf(lg0[u] * i0, vg0[u] + acc0[u], out0);
    out1 = fmaf(lg1[u] * i1, vg1[u] + acc1[u], out1);
  }
  outb[0][c] = out0; outb[1][c] = out1;
  float at0 = lobc, at1 = lobc;
#pragma unroll 4
  for (int d = 0; d < DD; d += 4) {
    float4 o0 = *(const float4*)&outb[0][d];
    float4 o1 = *(const float4*)&outb[1][d];
    float wa = ow[(d + 0) * 64 + c], wb = ow[(d + 1) * 64 + c];
    float wc = ow[(d + 2) * 64 + c], wd = ow[(d + 3) * 64 + c];
    at0 = fmaf(o0.x, wa, at0); at0 = fmaf(o0.y, wb, at0);
    at0 = fmaf(o0.z, wc, at0); at0 = fmaf(o0.w, wd, at0);
    at1 = fmaf(o1.x, wa, at1); at1 = fmaf(o1.y, wb, at1);
    at1 = fmaf(o1.z, wc, at1); at1 = fmaf(o1.w, wd, at1);
  }
  float t0v, t1v;
  {
    float res = at0 + hs0;
    float mean = wave_sum(res) * (1.0f / 64.0f);
    float dv = res - mean;
    float var = wave_sum(dv * dv) * (1.0f / 64.0f);
    float ivr = 1.0f / sqrtf(var + LNEPS);
    t0v = fmaf(g1c, dv * ivr, bt1c);
  }
  {
    float res = at1 + hs1;
    float mean = wave_sum(res) * (1.0f / 64.0f);
    float dv = res - mean;
    float var = wave_sum(dv * dv) * (1.0f / 64.0f);
    float ivr = 1.0f / sqrtf(var + LNEPS);
    t1v = fmaf(g1c, dv * ivr, bt1c);
  }
  // ================ ffn (fused, point-local; math identical to old ffn_kernel)
  tb[c][0] = t0v; tb[c][1] = t1v;
  float fb1a = fb1[c], fb1b = fb1[64 + c];
  float hA0 = fb1a, hA1 = fb1a, hB0 = fb1b, hB1 = fb1b;
#pragma unroll 4
  for (int d = 0; d < DD; d++) {
    float w0 = fw1[d * 128 + c], w1 = fw1[d * 128 + 64 + c];
    float2 yv = *(const float2*)&tb[d][0];
    hA0 = fmaf(yv.x, w0, hA0); hA1 = fmaf(yv.y, w0, hA1);
    hB0 = fmaf(yv.x, w1, hB0); hB1 = fmaf(yv.y, w1, hB1);
  }
  hA0 = gelu_exact(hA0); hA1 = gelu_exact(hA1);
  hB0 = gelu_exact(hB0); hB1 = gelu_exact(hB1);
  hb2[c][0] = hA0; hb2[c][1] = hA1;
  hb2[64 + c][0] = hB0; hb2[64 + c][1] = hB1;
  float fb2c = fb2[c], g2c = l2g[c], bt2c = l2b[c];
  float o0 = fb2c, o1 = fb2c;
#pragma unroll 4
  for (int j = 0; j < 128; j++) {
    float wv_ = fw2[j * 64 + c];
    float2 hv = *(const float2*)&hb2[j][0];
    o0 = fmaf(hv.x, wv_, o0); o1 = fmaf(hv.y, wv_, o1);
  }
  {
    float r = t0v + o0;
    float mean = wave_sum(r) * (1.0f / 64.0f);
    float dv = r - mean;
    float var = wave_sum(dv * dv) * (1.0f / 64.0f);
    float ivr = 1.0f / sqrtf(var + LNEPS);
    h[(size_t)p0 * 64 + c] = fmaf(g2c, dv * ivr, bt2c);
  }
  {
    float r = t1v + o1;
    float mean = wave_sum(r) * (1.0f / 64.0f);
    float dv = r - mean;
    float var = wave_sum(dv * dv) * (1.0f / 64.0f);
    float ivr = 1.0f / sqrtf(var + LNEPS);
    h[(size_t)(p0 + 1) * 64 + c] = fmaf(g2c, dv * ivr, bt2c);
  }
}

// ---------------------------------------------------------------- classifier proj + blockwise max-pool (XCD-pinned)
__global__ __launch_bounds__(256) void cls_kernel(
    const float* __restrict__ h, const float* __restrict__ cw, const float* __restrict__ cb,
    const float* __restrict__ cg, const float* __restrict__ cbeta, float* __restrict__ g) {
  __shared__ float lcw[DD * 128];
  __shared__ float lcb[128], lcg[128], lcbt[128];
  __shared__ __attribute__((aligned(16))) float hb[4][DD][4];
  __shared__ float wmax[4][128];
  int tid = threadIdx.x;
  for (int i = tid; i < DD * 128; i += 256) lcw[i] = cw[i];
  if (tid < 128) { lcb[tid] = cb[tid]; lcg[tid] = cg[tid]; lcbt[tid] = cbeta[tid]; }
  __syncthreads();
  int w = tid >> 6, c = tid & 63;
  int b = blockIdx.x & 7;             // XCD-pinned batch
  int blk = blockIdx.x >> 3;          // 128 block-positions per batch
  int base = b * NN + blk * 32;
  float m0 = 0.0f, m1 = 0.0f;
  for (int it = 0; it < 2; ++it) {
    int p0 = base + (w * 2 + it) * 4;
#pragma unroll
    for (int i = 0; i < 4; i++) hb[w][c][i] = h[(size_t)(p0 + i) * 64 + c];
    float a0[4], a1[4];
#pragma unroll
    for (int i = 0; i < 4; i++) { a0[i] = lcb[c]; a1[i] = lcb[64 + c]; }
#pragma unroll 4
    for (int d = 0; d < DD; d++) {
      float w0 = lcw[d * 128 + c], w1 = lcw[d * 128 + 64 + c];
      float4 hv = *(const float4*)&hb[w][d][0];
      a0[0] = fmaf(hv.x, w0, a0[0]); a0[1] = fmaf(hv.y, w0, a0[1]);
      a0[2] = fmaf(hv.z, w0, a0[2]); a0[3] = fmaf(hv.w, w0, a0[3]);
      a1[0] = fmaf(hv.x, w1, a1[0]); a1[1] = fmaf(hv.y, w1, a1[1]);
      a1[2] = fmaf(hv.z, w1, a1[2]); a1[3] = fmaf(hv.w, w1, a1[3]);
    }
#pragma unroll
    for (int i = 0; i < 4; i++) {
      m0 = fmaxf(m0, fmaxf(0.0f, fmaf(lcg[c] * a0[i], BNRS, lcbt[c])));
      m1 = fmaxf(m1, fmaxf(0.0f, fmaf(lcg[64 + c] * a1[i], BNRS, lcbt[64 + c])));
    }
  }
  wmax[w][c] = m0; wmax[w][64 + c] = m1;
  __syncthreads();
  if (tid < 128) {
    float mm = fmaxf(fmaxf(wmax[0][tid], wmax[1][tid]), fmaxf(wmax[2][tid], wmax[3][tid]));
    atomicMax((int*)&g[b * 128 + tid], __float_as_int(mm));  // values >= 0
  }
}

// ---------------------------------------------------------------- final head (per batch)
__global__ __launch_bounds__(128) void head_kernel(
    const float* __restrict__ g,
    const float* __restrict__ f1w, const float* __restrict__ f1b,
    const float* __restrict__ b1g, const float* __restrict__ b1b,
    const float* __restrict__ f2w, const float* __restrict__ f2b,
    const float* __restrict__ b2g, const float* __restrict__ b2b,
    const float* __restrict__ f3w, const float* __restrict__ f3b,
    float* __restrict__ out) {
  __shared__ float gb[128], g1[128], g2[64];
  int b = blockIdx.x, t = threadIdx.x;
  gb[t] = g[b * 128 + t];
  __syncthreads();
  float a = f1b[t];
#pragma unroll 4
  for (int d = 0; d < 128; d++) a = fmaf(gb[d], f1w[d * 128 + t], a);
  g1[t] = fmaxf(0.0f, fmaf(b1g[t] * a, BNRS, b1b[t]));
  __syncthreads();
  if (t < 64) {
    float a2 = f2b[t];
#pragma unroll 4
    for (int j = 0; j < 128; j++) a2 = fmaf(g1[j], f2w[j * 64 + t], a2);
    g2[t] = fmaxf(0.0f, fmaf(b2g[t] * a2, BNRS, b2b[t]));
  }
  __syncthreads();
  if (t < NCLS) {
    float a3 = f3b[t];
#pragma unroll
    for (int d = 0; d < 64; d++) a3 = fmaf(g2[d], f3w[d * NCLS + t], a3);
    out[b * NCLS + t] = a3;
  }
}

extern "C" void kernel_launch(void* const* d_in, const int* in_sizes, int n_in,
                              void* d_out, int out_size, void* d_ws, size_t ws_size,
                              hipStream_t stream) {
  const float* x    = (const float*)d_in[0];
  const float* ew1  = (const float*)d_in[1];
  const float* eb1  = (const float*)d_in[2];
  const float* ew2  = (const float*)d_in[3];
  const float* eb2  = (const float*)d_in[4];
  const float* wq   = (const float*)d_in[5];
  const float* bq   = (const float*)d_in[6];
  const float* wk   = (const float*)d_in[7];
  const float* bk   = (const float*)d_in[8];
  const float* wv   = (const float*)d_in[9];
  const float* bv   = (const float*)d_in[10];
  const float* pw1  = (const float*)d_in[11];
  const float* pb1  = (const float*)d_in[12];
  const float* pw2  = (const float*)d_in[13];
  const float* pb2  = (const float*)d_in[14];
  const float* aw   = (const float*)d_in[15];
  const float* ab   = (const float*)d_in[16];
  const float* ow   = (const float*)d_in[17];
  const float* ob   = (const float*)d_in[18];
  const float* l1g  = (const float*)d_in[19];
  const float* l1b  = (const float*)d_in[20];
  const float* l2g  = (const float*)d_in[21];
  const float* l2b  = (const float*)d_in[22];
  const float* fw1  = (const float*)d_in[23];
  const float* fb1  = (const float*)d_in[24];
  const float* fw2  = (const float*)d_in[25];
  const float* fb2  = (const float*)d_in[26];
  const float* cw   = (const float*)d_in[27];
  const float* cb   = (const float*)d_in[28];
  const float* cg   = (const float*)d_in[29];
  const float* cbeta= (const float*)d_in[30];
  const float* f1w  = (const float*)d_in[31];
  const float* f1b  = (const float*)d_in[32];
  const float* b1g  = (const float*)d_in[33];
  const float* b1b  = (const float*)d_in[34];
  const float* f2w  = (const float*)d_in[35];
  const float* f2b  = (const float*)d_in[36];
  const float* b2g  = (const float*)d_in[37];
  const float* b2b  = (const float*)d_in[38];
  const float* f3w  = (const float*)d_in[39];
  const float* f3b  = (const float*)d_in[40];

  const size_t P = (size_t)BB * NN;       // 32768 points
  float* ws = (float*)d_ws;
  float* h = ws;                          // P*64
  float* q = h + P * 64;
  float* k = q + P * 64;
  float* v = k + P * 64;
  int* idx = (int*)(v + P * 64);          // P*8 ints
  float* g = (float*)(idx + P * 8);       // B*128
  float4* ppg = (float4*)(g + BB * 128);  // P float4 (aligned: offset is 16B-multiple)

  zero_kernel<<<1, BB * 128, 0, stream>>>(g);
  embed_kernel<<<(int)(P / 4), 256, 0, stream>>>(x, ew1, eb1, ew2, eb2, h);
  knn_prep_kernel<<<(int)(P / 256), 256, 0, stream>>>(x, ppg);
  knn_kernel<<<BB * (NN / QPB), 1024, 0, stream>>>(ppg, idx);
  for (int l = 0; l < 2; l++) {
    qkv_kernel<<<(int)(P / 4), 64, 0, stream>>>(h, wq + l * DD * DD, bq + l * DD,
                                                wk + l * DD * DD, bk + l * DD,
                                                wv + l * DD * DD, bv + l * DD, q, k, v);
    attn_ffn_kernel<<<(int)(P / 2), 64, 0, stream>>>(
        x, h, q, k, v, idx,
        pw1 + l * 3 * DD, pb1 + l * DD, pw2 + l * DD * DD, pb2 + l * DD,
        aw + l * DD, ab + l, ow + l * DD * DD, ob + l * DD,
        l1g + l * DD, l1b + l * DD,
        fw1 + l * DD * 2 * DD, fb1 + l * 2 * DD, fw2 + l * 2 * DD * DD, fb2 + l * DD,
        l2g + l * DD, l2b + l * DD);
  }
  cls_kernel<<<BB * 128, 256, 0, stream>>>(h, cw, cb, cg, cbeta, g);
  head_kernel<<<BB, 128, 0, stream>>>(g, f1w, f1b, b1g, b1b, f2w, f2b, b2g, b2b, f3w, f3b,
                                      (float*)d_out);
}

// Round 18
// 364.515 us; speedup vs baseline: 1.1172x; 1.0069x over previous
//
#include <hip/hip_runtime.h>
#include <cmath>

#define BB 8
#define NN 4096
#define DD 64
#define KK 8
#define NCLS 2

constexpr float LNEPS = 1e-5f;
constexpr float BNRS = 0.9999950000374994f;      // 1/sqrt(1+1e-5)
constexpr float INVSQRT2 = 0.70710678118654752440f;

// knn decomposition: 64 queries/block x 16 candidate-splits (one per wave)
#define QPB 64
#define SPLITS 16
#define SUBSET 64     // pass-1 subset per split (16*64 = 1024-point bound set)

__device__ __forceinline__ float wave_sum(float v) {
#pragma unroll
  for (int m = 32; m > 0; m >>= 1) v += __shfl_xor(v, m, 64);
  return v;
}

__device__ __forceinline__ float gelu_exact(float x) {
  return 0.5f * x * (1.0f + erff(x * INVSQRT2));
}

// identical in both knn passes -> bit-identical distances
__device__ __forceinline__ float dist2(float4 q, float4 p) {
  float dot = fmaf(q.x, p.x, fmaf(q.y, p.y, q.z * p.z));
  return fmaf(-2.0f, dot, q.w + p.w);
}

// ---------------------------------------------------------------- zero g
__global__ void zero_kernel(float* g) { g[threadIdx.x] = 0.0f; }

// ---------------------------------------------------------------- embed: h = relu(x@ew1+eb1)@ew2+eb2
__global__ __launch_bounds__(256) void embed_kernel(
    const float* __restrict__ x, const float* __restrict__ ew1, const float* __restrict__ eb1,
    const float* __restrict__ ew2, const float* __restrict__ eb2, float* __restrict__ h) {
  __shared__ float h1[4][DD];
  int w = threadIdx.x >> 6, c = threadIdx.x & 63;
  int pt = ((blockIdx.x & 7) << 12) + (blockIdx.x >> 3) * 4 + w;
  const float* xp = x + (size_t)pt * 3;
  float x0 = xp[0], x1 = xp[1], x2 = xp[2];
  float a = fmaf(x0, ew1[c], fmaf(x1, ew1[64 + c], fmaf(x2, ew1[128 + c], eb1[c])));
  h1[w][c] = fmaxf(a, 0.0f);
  float s = eb2[c];
#pragma unroll 8
  for (int d = 0; d < DD; d++) s = fmaf(h1[w][d], ew2[d * 64 + c], s);
  h[(size_t)pt * 64 + c] = s;
}

// ---------------------------------------------------------------- knn prep: ppg[b*N+j] = (x,y,z,|p|^2)
__global__ __launch_bounds__(256) void knn_prep_kernel(const float* __restrict__ x,
                                                       float4* __restrict__ ppg) {
  int i = ((blockIdx.x & 7) << 12) + (blockIdx.x >> 3) * 256 + threadIdx.x;
  float a0 = x[3 * i + 0], a1 = x[3 * i + 1], a2 = x[3 * i + 2];
  ppg[i] = make_float4(a0, a1, a2, a0 * a0 + a1 * a1 + a2 * a2);
}

// ---------------------------------------------------------------- knn: exact top-8 (stable ties), 2-pass
// Pass-2 hit path: FIFO append to LDS; overflow (>8 hits/split, P~2e-4):
// replace-max-if-smaller keeps the split's 8 smallest hits -> provably exact.
__global__ __launch_bounds__(1024) void knn_kernel(const float4* __restrict__ ppg,
                                                   int* __restrict__ idx) {
  __shared__ union {
    float v[SPLITS * 8][QPB];       // pass-1 value lists
    double k[SPLITS * 8][QPB];      // pass-2 key lists (64 KB)
  } mb;
  __shared__ float thrq[QPB];
  int b = blockIdx.x & 7;           // XCD-pinned batch
  int qbase = (blockIdx.x >> 3) * QPB;
  const float4* pb = ppg + (size_t)b * NN;
  int ql = threadIdx.x & 63;
  int sp = __builtin_amdgcn_readfirstlane(threadIdx.x >> 6);  // wave id = split id (SGPR)
  float4 qp = pb[qbase + ql];
  const float4* cp = pb + sp * (NN / SPLITS);                 // scalar base

  // ---- pass 1: branchless top-8 distances over SUBSET candidates
  float bd[8];
#pragma unroll
  for (int u = 0; u < 8; u++) bd[u] = INFINITY;
#pragma unroll 4
  for (int jj = 0; jj < SUBSET; ++jj) {
    float d2 = dist2(qp, cp[jj]);
#pragma unroll
    for (int u = 7; u > 0; --u) bd[u] = fminf(bd[u], fmaxf(bd[u - 1], d2));
    bd[0] = fminf(bd[0], d2);
  }
#pragma unroll
  for (int u = 0; u < 8; u++) mb.v[sp * 8 + u][ql] = bd[u];
  __syncthreads();

  // ---- U merge stage 1
  if (sp < 8) {
    float cd[8];
#pragma unroll
    for (int u = 0; u < 8; u++) cd[u] = INFINITY;
    int base = sp * 16;
#pragma unroll
    for (int e = 0; e < 16; e++) {
      float vv = mb.v[base + e][ql];
#pragma unroll
      for (int u = 7; u > 0; --u) cd[u] = fminf(cd[u], fmaxf(cd[u - 1], vv));
      cd[0] = fminf(cd[0], vv);
    }
#pragma unroll
    for (int u = 0; u < 8; u++) mb.v[base + u][ql] = cd[u];
  }
  __syncthreads();

  // ---- U merge stage 2
  if (sp == 0) {
    float cd[8];
#pragma unroll
    for (int u = 0; u < 8; u++) cd[u] = INFINITY;
    for (int m = 0; m < 8; m++) {
      for (int e = 0; e < 8; e++) {
        float vv = mb.v[m * 16 + e][ql];
        if (__all(vv >= cd[7])) break;
#pragma unroll
        for (int u = 7; u > 0; --u) cd[u] = fminf(cd[u], fmaxf(cd[u - 1], vv));
        cd[0] = fminf(cd[0], vv);
      }
    }
    thrq[ql] = cd[7];
  }
  __syncthreads();
  float U = thrq[ql];

  // ---- init key slots
#pragma unroll
  for (int u = 0; u < 8; u++) mb.k[sp * 8 + u][ql] = INFINITY;

  // ---- pass 2: FIFO-collect hits (d2<=U) per split; overflow -> replace-max
  int cnt = 0;
#pragma unroll 4
  for (int jj = 0; jj < NN / SPLITS; ++jj) {
    float d2 = dist2(qp, cp[jj]);
    if (d2 <= U) {
      double key = __hiloint2double(__float_as_int(d2), sp * (NN / SPLITS) + jj);
      if (cnt < 8) {
        mb.k[sp * 8 + cnt][ql] = key;
        cnt++;
      } else {
        double mx = mb.k[sp * 8 + 0][ql];
        int mi = 0;
#pragma unroll
        for (int u = 1; u < 8; u++) {
          double tv = mb.k[sp * 8 + u][ql];
          if (tv > mx) { mx = tv; mi = u; }
        }
        if (key < mx) mb.k[sp * 8 + mi][ql] = key;
      }
    }
  }
  __syncthreads();

  // ---- key merge stage 1 (network accepts unsorted input; output sorted)
  if (sp < 8) {
    double cd[8];
#pragma unroll
    for (int u = 0; u < 8; u++) cd[u] = INFINITY;
    int base = sp * 16;
#pragma unroll
    for (int e = 0; e < 16; e++) {
      double key = mb.k[base + e][ql];
#pragma unroll
      for (int u = 7; u > 0; --u) cd[u] = fmin(cd[u], fmax(cd[u - 1], key));
      cd[0] = fmin(cd[0], key);
    }
#pragma unroll
    for (int u = 0; u < 8; u++) mb.k[base + u][ql] = cd[u];
  }
  __syncthreads();

  // ---- key merge stage 2 + write (stage-1 outputs sorted -> __all-break ok)
  if (sp == 0) {
    double cd[8];
#pragma unroll
    for (int u = 0; u < 8; u++) cd[u] = INFINITY;
    for (int m = 0; m < 8; m++) {
      for (int e = 0; e < 8; e++) {
        double key = mb.k[m * 16 + e][ql];
        if (__all(key >= cd[7])) break;
#pragma unroll
        for (int u = 7; u > 0; --u) cd[u] = fmin(cd[u], fmax(cd[u - 1], key));
        cd[0] = fmin(cd[0], key);
      }
    }
    int* op = idx + ((size_t)b * NN + qbase + ql) * 8;
#pragma unroll
    for (int u = 0; u < 8; u++) op[u] = __double2loint(cd[u]);
  }
}

// ---------------------------------------------------------------- qkv projection: 1-wave blocks, 4 points/wave
__global__ __launch_bounds__(64) void qkv_kernel(
    const float* __restrict__ h, const float* __restrict__ wq, const float* __restrict__ bq,
    const float* __restrict__ wk, const float* __restrict__ bk,
    const float* __restrict__ wv, const float* __restrict__ bv,
    float* __restrict__ q, float* __restrict__ k, float* __restrict__ v) {
  __shared__ __attribute__((aligned(16))) float hb[DD][4];
  int c = threadIdx.x;
  int b = blockIdx.x & 7, pos = blockIdx.x >> 3;   // 1024 positions per batch
  int p0 = (b << 12) + pos * 4;
#pragma unroll
  for (int i = 0; i < 4; i++) hb[c][i] = h[(size_t)(p0 + i) * 64 + c];
  float bqc = bq[c], bkc = bk[c], bvc = bv[c];
  float aq[4], ak[4], av[4];
#pragma unroll
  for (int i = 0; i < 4; i++) { aq[i] = bqc; ak[i] = bkc; av[i] = bvc; }
#pragma unroll 4
  for (int d = 0; d < DD; d++) {
    float wq_ = wq[d * 64 + c], wk_ = wk[d * 64 + c], wv_ = wv[d * 64 + c];
    float4 hh = *(const float4*)&hb[d][0];
    aq[0] = fmaf(hh.x, wq_, aq[0]); aq[1] = fmaf(hh.y, wq_, aq[1]);
    aq[2] = fmaf(hh.z, wq_, aq[2]); aq[3] = fmaf(hh.w, wq_, aq[3]);
    ak[0] = fmaf(hh.x, wk_, ak[0]); ak[1] = fmaf(hh.y, wk_, ak[1]);
    ak[2] = fmaf(hh.z, wk_, ak[2]); ak[3] = fmaf(hh.w, wk_, ak[3]);
    av[0] = fmaf(hh.x, wv_, av[0]); av[1] = fmaf(hh.y, wv_, av[1]);
    av[2] = fmaf(hh.z, wv_, av[2]); av[3] = fmaf(hh.w, wv_, av[3]);
  }
#pragma unroll
  for (int i = 0; i < 4; i++) {
    q[(size_t)(p0 + i) * 64 + c] = aq[i];
    k[(size_t)(p0 + i) * 64 + c] = ak[i];
    v[(size_t)(p0 + i) * 64 + c] = av[i];
  }
}

// ---------------------------------------------------------------- fused attention+ffn: 1-wave blocks, 2 points/wave
// attn -> t (registers) -> ffn -> h, all point-local after the k/v gathers.
// s_setprio(1) around dense FMA clusters (T5: helps when independent waves sit
// at different phases -- exactly this kernel's regime; measured +4-7% on attn).
__global__ __launch_bounds__(64) void attn_ffn_kernel(
    const float* __restrict__ x, float* h,
    const float* __restrict__ q, const float* __restrict__ kk, const float* __restrict__ vv,
    const int* __restrict__ idx,
    const float* __restrict__ pw1, const float* __restrict__ pb1,
    const float* __restrict__ pw2, const float* __restrict__ pb2,
    const float* __restrict__ aw, const float* __restrict__ ab,
    const float* __restrict__ ow, const float* __restrict__ ob,
    const float* __restrict__ l1g, const float* __restrict__ l1b,
    const float* __restrict__ fw1, const float* __restrict__ fb1,
    const float* __restrict__ fw2, const float* __restrict__ fb2,
    const float* __restrict__ l2g, const float* __restrict__ l2b) {
  __shared__ __attribute__((aligned(16))) float h1b[2][DD][8];   // 4KB
  __shared__ __attribute__((aligned(16))) float outb[2][DD];     // 0.5KB
  __shared__ __attribute__((aligned(8)))  float tb[DD][2];       // 0.5KB
  __shared__ __attribute__((aligned(8)))  float hb2[128][2];     // 1KB
  int c = threadIdx.x;
  int b = blockIdx.x & 7;                 // XCD-pinned batch
  int n0 = (blockIdx.x >> 3) * 2;         // 2048 positions per batch
  int p0 = (b << 12) + n0;
  const float* xb = x + (size_t)b * NN * 3;
  float w1c0 = pw1[c], w1c1 = pw1[64 + c], w1c2 = pw1[128 + c], b1c = pb1[c];
  float pb2c = pb2[c], lawc = aw[c], lobc = ob[c], g1c = l1g[c], bt1c = l1b[c];
  float lab = ab[0];
  float hs0 = h[(size_t)p0 * 64 + c], hs1 = h[(size_t)(p0 + 1) * 64 + c];
  float qs0 = q[(size_t)p0 * 64 + c], qs1 = q[(size_t)(p0 + 1) * 64 + c];
  int nb[2][8];
#pragma unroll
  for (int u = 0; u < 8; u++) {
    nb[0][u] = idx[(size_t)p0 * 8 + u];
    nb[1][u] = idx[(size_t)(p0 + 1) * 8 + u];
  }
  // ---- prefetch all k/v gather rows NOW; latency hides under pe1+pe2 compute
  float kv0[8], kv1[8], vg0[8], vg1[8];
#pragma unroll
  for (int u = 0; u < 8; u++) {
    kv0[u] = kk[((size_t)(b << 12) + nb[0][u]) * 64 + c];
    kv1[u] = kk[((size_t)(b << 12) + nb[1][u]) * 64 + c];
    vg0[u] = vv[((size_t)(b << 12) + nb[0][u]) * 64 + c];
    vg1[u] = vv[((size_t)(b << 12) + nb[1][u]) * 64 + c];
  }
#pragma unroll
  for (int pt = 0; pt < 2; ++pt) {
    int n = n0 + pt;
    float px0 = xb[n * 3 + 0], px1 = xb[n * 3 + 1], px2 = xb[n * 3 + 2];
    float h1v[8];
#pragma unroll
    for (int u = 0; u < 8; u++) {
      int m = nb[pt][u];
      float d0 = px0 - xb[m * 3 + 0], d1 = px1 - xb[m * 3 + 1], d2 = px2 - xb[m * 3 + 2];
      h1v[u] = fmaxf(fmaf(d0, w1c0, fmaf(d1, w1c1, fmaf(d2, w1c2, b1c))), 0.0f);
    }
    *(float4*)&h1b[pt][c][0] = make_float4(h1v[0], h1v[1], h1v[2], h1v[3]);
    *(float4*)&h1b[pt][c][4] = make_float4(h1v[4], h1v[5], h1v[6], h1v[7]);
  }
  float acc0[8], acc1[8];
#pragma unroll
  for (int u = 0; u < 8; u++) { acc0[u] = pb2c; acc1[u] = pb2c; }
  __builtin_amdgcn_s_setprio(1);          // dense pe2 burst
#pragma unroll 2
  for (int d = 0; d < DD; d++) {
    float wv_ = pw2[d * 64 + c];
    float4 a0 = *(const float4*)&h1b[0][d][0];
    float4 b0 = *(const float4*)&h1b[0][d][4];
    float4 a1 = *(const float4*)&h1b[1][d][0];
    float4 b1 = *(const float4*)&h1b[1][d][4];
    acc0[0] = fmaf(a0.x, wv_, acc0[0]); acc0[1] = fmaf(a0.y, wv_, acc0[1]);
    acc0[2] = fmaf(a0.z, wv_, acc0[2]); acc0[3] = fmaf(a0.w, wv_, acc0[3]);
    acc0[4] = fmaf(b0.x, wv_, acc0[4]); acc0[5] = fmaf(b0.y, wv_, acc0[5]);
    acc0[6] = fmaf(b0.z, wv_, acc0[6]); acc0[7] = fmaf(b0.w, wv_, acc0[7]);
    acc1[0] = fmaf(a1.x, wv_, acc1[0]); acc1[1] = fmaf(a1.y, wv_, acc1[1]);
    acc1[2] = fmaf(a1.z, wv_, acc1[2]); acc1[3] = fmaf(a1.w, wv_, acc1[3]);
    acc1[4] = fmaf(b1.x, wv_, acc1[4]); acc1[5] = fmaf(b1.y, wv_, acc1[5]);
    acc1[6] = fmaf(b1.z, wv_, acc1[6]); acc1[7] = fmaf(b1.w, wv_, acc1[7]);
  }
  __builtin_amdgcn_s_setprio(0);
  float lg0[8], lg1[8];
#pragma unroll
  for (int u = 0; u < 8; u++) {
    lg0[u] = wave_sum((qs0 - kv0[u] + acc0[u]) * lawc) + lab;
    lg1[u] = wave_sum((qs1 - kv1[u] + acc1[u]) * lawc) + lab;
  }
  float mx0 = lg0[0], mx1 = lg1[0];
#pragma unroll
  for (int u = 1; u < 8; u++) { mx0 = fmaxf(mx0, lg0[u]); mx1 = fmaxf(mx1, lg1[u]); }
  float s0 = 0.0f, s1 = 0.0f;
#pragma unroll
  for (int u = 0; u < 8; u++) {
    lg0[u] = expf(lg0[u] - mx0); s0 += lg0[u];
    lg1[u] = expf(lg1[u] - mx1); s1 += lg1[u];
  }
  float i0 = 1.0f / s0, i1 = 1.0f / s1;
  float out0 = 0.0f, out1 = 0.0f;
#pragma unroll
  for (int u = 0; u < 8; u++) {
    out0 = fmaf(lg0[u] * i0, vg0[u] + acc0[u], out0);
    out1 = fmaf(lg1[u] * i1, vg1[u] + acc1[u], out1);
  }
  outb[0][c] = out0; outb[1][c] = out1;
  float at0 = lobc, at1 = lobc;
  __builtin_amdgcn_s_setprio(1);          // dense ow burst
#pragma unroll 4
  for (int d = 0; d < DD; d += 4) {
    float4 o0 = *(const float4*)&outb[0][d];
    float4 o1 = *(const float4*)&outb[1][d];
    float wa = ow[(d + 0) * 64 + c], wb = ow[(d + 1) * 64 + c];
    float wc = ow[(d + 2) * 64 + c], wd = ow[(d + 3) * 64 + c];
    at0 = fmaf(o0.x, wa, at0); at0 = fmaf(o0.y, wb, at0);
    at0 = fmaf(o0.z, wc, at0); at0 = fmaf(o0.w, wd, at0);
    at1 = fmaf(o1.x, wa, at1); at1 = fmaf(o1.y, wb, at1);
    at1 = fmaf(o1.z, wc, at1); at1 = fmaf(o1.w, wd, at1);
  }
  __builtin_amdgcn_s_setprio(0);
  float t0v, t1v;
  {
    float res = at0 + hs0;
    float mean = wave_sum(res) * (1.0f / 64.0f);
    float dv = res - mean;
    float var = wave_sum(dv * dv) * (1.0f / 64.0f);
    float ivr = 1.0f / sqrtf(var + LNEPS);
    t0v = fmaf(g1c, dv * ivr, bt1c);
  }
  {
    float res = at1 + hs1;
    float mean = wave_sum(res) * (1.0f / 64.0f);
    float dv = res - mean;
    float var = wave_sum(dv * dv) * (1.0f / 64.0f);
    float ivr = 1.0f / sqrtf(var + LNEPS);
    t1v = fmaf(g1c, dv * ivr, bt1c);
  }
  // ================ ffn (fused, point-local; math identical to old ffn_kernel)
  tb[c][0] = t0v; tb[c][1] = t1v;
  float fb1a = fb1[c], fb1b = fb1[64 + c];
  float hA0 = fb1a, hA1 = fb1a, hB0 = fb1b, hB1 = fb1b;
  __builtin_amdgcn_s_setprio(1);          // dense fc1+fc2 burst
#pragma unroll 4
  for (int d = 0; d < DD; d++) {
    float w0 = fw1[d * 128 + c], w1 = fw1[d * 128 + 64 + c];
    float2 yv = *(const float2*)&tb[d][0];
    hA0 = fmaf(yv.x, w0, hA0); hA1 = fmaf(yv.y, w0, hA1);
    hB0 = fmaf(yv.x, w1, hB0); hB1 = fmaf(yv.y, w1, hB1);
  }
  __builtin_amdgcn_s_setprio(0);
  hA0 = gelu_exact(hA0); hA1 = gelu_exact(hA1);
  hB0 = gelu_exact(hB0); hB1 = gelu_exact(hB1);
  hb2[c][0] = hA0; hb2[c][1] = hA1;
  hb2[64 + c][0] = hB0; hb2[64 + c][1] = hB1;
  float fb2c = fb2[c], g2c = l2g[c], bt2c = l2b[c];
  float o0 = fb2c, o1 = fb2c;
  __builtin_amdgcn_s_setprio(1);
#pragma unroll 4
  for (int j = 0; j < 128; j++) {
    float wv_ = fw2[j * 64 + c];
    float2 hv = *(const float2*)&hb2[j][0];
    o0 = fmaf(hv.x, wv_, o0); o1 = fmaf(hv.y, wv_, o1);
  }
  __builtin_amdgcn_s_setprio(0);
  {
    float r = t0v + o0;
    float mean = wave_sum(r) * (1.0f / 64.0f);
    float dv = r - mean;
    float var = wave_sum(dv * dv) * (1.0f / 64.0f);
    float ivr = 1.0f / sqrtf(var + LNEPS);
    h[(size_t)p0 * 64 + c] = fmaf(g2c, dv * ivr, bt2c);
  }
  {
    float r = t1v + o1;
    float mean = wave_sum(r) * (1.0f / 64.0f);
    float dv = r - mean;
    float var = wave_sum(dv * dv) * (1.0f / 64.0f);
    float ivr = 1.0f / sqrtf(var + LNEPS);
    h[(size_t)(p0 + 1) * 64 + c] = fmaf(g2c, dv * ivr, bt2c);
  }
}

// ---------------------------------------------------------------- classifier proj + blockwise max-pool (XCD-pinned)
__global__ __launch_bounds__(256) void cls_kernel(
    const float* __restrict__ h, const float* __restrict__ cw, const float* __restrict__ cb,
    const float* __restrict__ cg, const float* __restrict__ cbeta, float* __restrict__ g) {
  __shared__ float lcw[DD * 128];
  __shared__ float lcb[128], lcg[128], lcbt[128];
  __shared__ __attribute__((aligned(16))) float hb[4][DD][4];
  __shared__ float wmax[4][128];
  int tid = threadIdx.x;
  for (int i = tid; i < DD * 128; i += 256) lcw[i] = cw[i];
  if (tid < 128) { lcb[tid] = cb[tid]; lcg[tid] = cg[tid]; lcbt[tid] = cbeta[tid]; }
  __syncthreads();
  int w = tid >> 6, c = tid & 63;
  int b = blockIdx.x & 7;             // XCD-pinned batch
  int blk = blockIdx.x >> 3;          // 128 block-positions per batch
  int base = b * NN + blk * 32;
  float m0 = 0.0f, m1 = 0.0f;
  for (int it = 0; it < 2; ++it) {
    int p0 = base + (w * 2 + it) * 4;
#pragma unroll
    for (int i = 0; i < 4; i++) hb[w][c][i] = h[(size_t)(p0 + i) * 64 + c];
    float a0[4], a1[4];
#pragma unroll
    for (int i = 0; i < 4; i++) { a0[i] = lcb[c]; a1[i] = lcb[64 + c]; }
#pragma unroll 4
    for (int d = 0; d < DD; d++) {
      float w0 = lcw[d * 128 + c], w1 = lcw[d * 128 + 64 + c];
      float4 hv = *(const float4*)&hb[w][d][0];
      a0[0] = fmaf(hv.x, w0, a0[0]); a0[1] = fmaf(hv.y, w0, a0[1]);
      a0[2] = fmaf(hv.z, w0, a0[2]); a0[3] = fmaf(hv.w, w0, a0[3]);
      a1[0] = fmaf(hv.x, w1, a1[0]); a1[1] = fmaf(hv.y, w1, a1[1]);
      a1[2] = fmaf(hv.z, w1, a1[2]); a1[3] = fmaf(hv.w, w1, a1[3]);
    }
#pragma unroll
    for (int i = 0; i < 4; i++) {
      m0 = fmaxf(m0, fmaxf(0.0f, fmaf(lcg[c] * a0[i], BNRS, lcbt[c])));
      m1 = fmaxf(m1, fmaxf(0.0f, fmaf(lcg[64 + c] * a1[i], BNRS, lcbt[64 + c])));
    }
  }
  wmax[w][c] = m0; wmax[w][64 + c] = m1;
  __syncthreads();
  if (tid < 128) {
    float mm = fmaxf(fmaxf(wmax[0][tid], wmax[1][tid]), fmaxf(wmax[2][tid], wmax[3][tid]));
    atomicMax((int*)&g[b * 128 + tid], __float_as_int(mm));  // values >= 0
  }
}

// ---------------------------------------------------------------- final head (per batch)
__global__ __launch_bounds__(128) void head_kernel(
    const float* __restrict__ g,
    const float* __restrict__ f1w, const float* __restrict__ f1b,
    const float* __restrict__ b1g, const float* __restrict__ b1b,
    const float* __restrict__ f2w, const float* __restrict__ f2b,
    const float* __restrict__ b2g, const float* __restrict__ b2b,
    const float* __restrict__ f3w, const float* __restrict__ f3b,
    float* __restrict__ out) {
  __shared__ float gb[128], g1[128], g2[64];
  int b = blockIdx.x, t = threadIdx.x;
  gb[t] = g[b * 128 + t];
  __syncthreads();
  float a = f1b[t];
#pragma unroll 4
  for (int d = 0; d < 128; d++) a = fmaf(gb[d], f1w[d * 128 + t], a);
  g1[t] = fmaxf(0.0f, fmaf(b1g[t] * a, BNRS, b1b[t]));
  __syncthreads();
  if (t < 64) {
    float a2 = f2b[t];
#pragma unroll 4
    for (int j = 0; j < 128; j++) a2 = fmaf(g1[j], f2w[j * 64 + t], a2);
    g2[t] = fmaxf(0.0f, fmaf(b2g[t] * a2, BNRS, b2b[t]));
  }
  __syncthreads();
  if (t < NCLS) {
    float a3 = f3b[t];
#pragma unroll
    for (int d = 0; d < 64; d++) a3 = fmaf(g2[d], f3w[d * NCLS + t], a3);
    out[b * NCLS + t] = a3;
  }
}

extern "C" void kernel_launch(void* const* d_in, const int* in_sizes, int n_in,
                              void* d_out, int out_size, void* d_ws, size_t ws_size,
                              hipStream_t stream) {
  const float* x    = (const float*)d_in[0];
  const float* ew1  = (const float*)d_in[1];
  const float* eb1  = (const float*)d_in[2];
  const float* ew2  = (const float*)d_in[3];
  const float* eb2  = (const float*)d_in[4];
  const float* wq   = (const float*)d_in[5];
  const float* bq   = (const float*)d_in[6];
  const float* wk   = (const float*)d_in[7];
  const float* bk   = (const float*)d_in[8];
  const float* wv   = (const float*)d_in[9];
  const float* bv   = (const float*)d_in[10];
  const float* pw1  = (const float*)d_in[11];
  const float* pb1  = (const float*)d_in[12];
  const float* pw2  = (const float*)d_in[13];
  const float* pb2  = (const float*)d_in[14];
  const float* aw   = (const float*)d_in[15];
  const float* ab   = (const float*)d_in[16];
  const float* ow   = (const float*)d_in[17];
  const float* ob   = (const float*)d_in[18];
  const float* l1g  = (const float*)d_in[19];
  const float* l1b  = (const float*)d_in[20];
  const float* l2g  = (const float*)d_in[21];
  const float* l2b  = (const float*)d_in[22];
  const float* fw1  = (const float*)d_in[23];
  const float* fb1  = (const float*)d_in[24];
  const float* fw2  = (const float*)d_in[25];
  const float* fb2  = (const float*)d_in[26];
  const float* cw   = (const float*)d_in[27];
  const float* cb   = (const float*)d_in[28];
  const float* cg   = (const float*)d_in[29];
  const float* cbeta= (const float*)d_in[30];
  const float* f1w  = (const float*)d_in[31];
  const float* f1b  = (const float*)d_in[32];
  const float* b1g  = (const float*)d_in[33];
  const float* b1b  = (const float*)d_in[34];
  const float* f2w  = (const float*)d_in[35];
  const float* f2b  = (const float*)d_in[36];
  const float* b2g  = (const float*)d_in[37];
  const float* b2b  = (const float*)d_in[38];
  const float* f3w  = (const float*)d_in[39];
  const float* f3b  = (const float*)d_in[40];

  const size_t P = (size_t)BB * NN;       // 32768 points
  float* ws = (float*)d_ws;
  float* h = ws;                          // P*64
  float* q = h + P * 64;
  float* k = q + P * 64;
  float* v = k + P * 64;
  int* idx = (int*)(v + P * 64);          // P*8 ints
  float* g = (float*)(idx + P * 8);       // B*128
  float4* ppg = (float4*)(g + BB * 128);  // P float4 (aligned: offset is 16B-multiple)

  zero_kernel<<<1, BB * 128, 0, stream>>>(g);
  embed_kernel<<<(int)(P / 4), 256, 0, stream>>>(x, ew1, eb1, ew2, eb2, h);
  knn_prep_kernel<<<(int)(P / 256), 256, 0, stream>>>(x, ppg);
  knn_kernel<<<BB * (NN / QPB), 1024, 0, stream>>>(ppg, idx);
  for (int l = 0; l < 2; l++) {
    qkv_kernel<<<(int)(P / 4), 64, 0, stream>>>(h, wq + l * DD * DD, bq + l * DD,
                                                wk + l * DD * DD, bk + l * DD,
                                                wv + l * DD * DD, bv + l * DD, q, k, v);
    attn_ffn_kernel<<<(int)(P / 2), 64, 0, stream>>>(
        x, h, q, k, v, idx,
        pw1 + l * 3 * DD, pb1 + l * DD, pw2 + l * DD * DD, pb2 + l * DD,
        aw + l * DD, ab + l, ow + l * DD * DD, ob + l * DD,
        l1g + l * DD, l1b + l * DD,
        fw1 + l * DD * 2 * DD, fb1 + l * 2 * DD, fw2 + l * 2 * DD * DD, fb2 + l * DD,
        l2g + l * DD, l2b + l * DD);
  }
  cls_kernel<<<BB * 128, 256, 0, stream>>>(h, cw, cb, cg, cbeta, g);
  head_kernel<<<BB, 128, 0, stream>>>(g, f1w, f1b, b1g, b1b, f2w, f2b, b2g, b2b, f3w, f3b,
                                      (float*)d_out);
}